// Round 7
// baseline (5975.699 us; speedup 1.0000x reference)
//
#include <hip/hip_runtime.h>
#include <stdint.h>
#include <stddef.h>

// ---------- constants ----------
#define B_    64
#define N_    32
#define NREL_ 992
#define D_    512
#define E_    128
#define H_    512
#define T_    16
#define MROWS (B_ * NREL_)   // 63488
#define MOBJ  (B_ * N_)      // 2048

typedef unsigned short ushort_t;
typedef __attribute__((ext_vector_type(8))) short bf16x8;   // 8 bf16 = 4 VGPRs (MFMA A/B frag)
typedef __attribute__((ext_vector_type(4))) float f32x4;    // MFMA C/D frag

typedef __attribute__((address_space(1))) const void gvoid;
typedef __attribute__((address_space(3))) void lvoid;

__device__ __forceinline__ float bf2f(ushort_t u) {
  union { unsigned int i; float f; } v; v.i = ((unsigned int)u) << 16; return v.f;
}
__device__ __forceinline__ ushort_t f2bf(float f) {   // round-to-nearest-even
  union { float f; unsigned int i; } v; v.f = f;
  unsigned int u = v.i;
  u += 0x7FFFu + ((u >> 16) & 1u);
  return (ushort_t)(u >> 16);
}
__device__ __forceinline__ void gload_lds16(const void* g, void* l) {
  __builtin_amdgcn_global_load_lds((gvoid*)g, (lvoid*)l, 16, 0, 0);
}

// ---------- TMx128 MFMA GEMM, 3xBF16 fp32 emulation ----------
// BK=32 K-chunks, 4-deep LDS pipeline (stage 3 tiles ahead, vmcnt(12/9) —
// waits target loads issued >=3 iterations ago so L2/HBM latency is covered),
// raw s_barrier, setprio(1) around MFMA clusters. XOR bank-swizzle for 64B
// rows: slot ^= (row>>1)&3, applied as pre-swizzled global SOURCE (linear
// gload_lds dest) + swizzled ds_read address (involution; balanced banks).
// MODE 0: A rows plain split [M][2K] = [hi K | lo K].
// MODE 2: logical row m = concat(ent[m](512), agg[m](128)); K=640.
// K-accumulation order identical to the BK=64 version (bit-identical output).
template<int MODE, bool RELU, bool WBF16, bool WF32, int TM>
__global__ __launch_bounds__(256) void gemm_k(
    const ushort_t* __restrict__ A, const ushort_t* __restrict__ A2,
    const ushort_t* __restrict__ Bt, const float* __restrict__ bias,
    ushort_t* __restrict__ C, float* __restrict__ Cf,
    int M, int N, int K)
{
  constexpr int MI = TM / 32;          // A frags per wave per chunk
  constexpr int AR = TM / 64;          // A staging rounds per chunk
  constexpr int LPT = AR + 2;          // gload_lds per thread per chunk
  __shared__ ushort_t As[4][TM * 32];
  __shared__ ushort_t Bs[4][128 * 32];

  const int tid  = threadIdx.x;
  const int lane = tid & 63;
  const int wave = tid >> 6;

  // bijective XCD-chunked tile remap (m204)
  const int nwg  = gridDim.x * gridDim.y;
  const int orig = blockIdx.y * gridDim.x + blockIdx.x;
  const int xcd  = orig & 7;
  const int q    = nwg >> 3, r = nwg & 7;
  const int nid  = (xcd < r ? xcd * (q + 1) : r * (q + 1) + (xcd - r) * q) + (orig >> 3);
  const int m0 = (nid / gridDim.x) * TM;
  const int n0 = (nid % gridDim.x) * 128;

  const int wr = (wave >> 1) * (TM / 2);
  const int wc = (wave & 1) * 64;

  const int srow = tid >> 2;                              // 0..63 staging row in a round
  const int scol = (((tid & 3) ^ ((srow >> 1) & 3)) * 8); // swizzled source col (elements)

  long aoff[AR]; long aoff2[AR];
#pragma unroll
  for (int rr = 0; rr < AR; ++rr) {
    int m = m0 + rr * 64 + srow;
    if (MODE == 0) { aoff[rr] = (long)m * (2 * K) + scol; aoff2[rr] = 0; }
    else           { aoff[rr] = (long)m * 1024 + scol; aoff2[rr] = (long)m * 256 + scol; }
  }
  long boff[2];
#pragma unroll
  for (int rr = 0; rr < 2; ++rr) boff[rr] = (long)(n0 + rr * 64 + srow) * (3 * K) + scol;

  const int NT = (3 * K) >> 5;   // K-chunks of 32

  auto stage = [&](int kt, int b) {
    const int kpp = kt * 32;
    const int seg = (kpp >= 2 * K) ? 2 : ((kpp >= K) ? 1 : 0);
    const int k   = kpp - seg * K;
    const bool lop = (seg == 1);
#pragma unroll
    for (int rr = 0; rr < AR; ++rr) {
      const ushort_t* src;
      if (MODE == 0) {
        src = A + aoff[rr] + (lop ? K : 0) + k;
      } else {
        if (k < 512) src = A  + aoff[rr]  + (lop ? 512 : 0) + k;
        else         src = A2 + aoff2[rr] + (lop ? 128 : 0) + (k - 512);
      }
      gload_lds16(src, &As[b][(rr * 64 + wave * 16) * 32]);
    }
#pragma unroll
    for (int rr = 0; rr < 2; ++rr)
      gload_lds16(Bt + boff[rr] + kpp, &Bs[b][(rr * 64 + wave * 16) * 32]);
  };

  f32x4 zero = {0.f, 0.f, 0.f, 0.f};
  f32x4 acc[MI][4];
#pragma unroll
  for (int i = 0; i < MI; ++i)
#pragma unroll
    for (int j = 0; j < 4; ++j) acc[i][j] = zero;

  // prologue: 3 chunks in flight
  stage(0, 0); stage(1, 1); stage(2, 2);

  for (int kt = 0; kt < NT; ++kt) {
    const int b = kt & 3;
    if (kt + 3 < NT) {
      stage(kt + 3, (kt + 3) & 3);     // buf (kt-1)&3: all waves past bar2(kt-1) -> free
      if constexpr (LPT == 4) asm volatile("s_waitcnt vmcnt(12)" ::: "memory");
      else                    asm volatile("s_waitcnt vmcnt(9)"  ::: "memory");
    } else if (kt + 2 < NT) {
      if constexpr (LPT == 4) asm volatile("s_waitcnt vmcnt(8)" ::: "memory");
      else                    asm volatile("s_waitcnt vmcnt(6)" ::: "memory");
    } else if (kt + 1 < NT) {
      if constexpr (LPT == 4) asm volatile("s_waitcnt vmcnt(4)" ::: "memory");
      else                    asm volatile("s_waitcnt vmcnt(3)" ::: "memory");
    } else {
      asm volatile("s_waitcnt vmcnt(0)" ::: "memory");
    }
    __builtin_amdgcn_s_barrier();
    asm volatile("" ::: "memory");

    const int l15 = lane & 15;
    bf16x8 af[MI];
#pragma unroll
    for (int i = 0; i < MI; ++i) {
      const int row = wr + i * 16 + l15;
      const int slot = (lane >> 4) ^ ((row >> 1) & 3);
      af[i] = *(const bf16x8*)&As[b][row * 32 + slot * 8];
    }
#pragma unroll
    for (int jh = 0; jh < 2; ++jh) {
      bf16x8 bfr[2];
#pragma unroll
      for (int jj = 0; jj < 2; ++jj) {
        const int row = wc + (jh * 2 + jj) * 16 + l15;
        const int slot = (lane >> 4) ^ ((row >> 1) & 3);
        bfr[jj] = *(const bf16x8*)&Bs[b][row * 32 + slot * 8];
      }
      __builtin_amdgcn_s_setprio(1);
#pragma unroll
      for (int i = 0; i < MI; ++i)
#pragma unroll
        for (int jj = 0; jj < 2; ++jj)
          acc[i][jh * 2 + jj] =
              __builtin_amdgcn_mfma_f32_16x16x32_bf16(af[i], bfr[jj], acc[i][jh * 2 + jj], 0, 0, 0);
      __builtin_amdgcn_s_setprio(0);
    }

    asm volatile("" ::: "memory");
    __builtin_amdgcn_s_barrier();   // protects buf (kt)&3 from next iter's stage(kt+4)
    asm volatile("" ::: "memory");
  }

  const long strideC = 2 * (long)N;
#pragma unroll
  for (int j = 0; j < 4; ++j) {
    const int col = n0 + wc + j * 16 + (lane & 15);
    const float bv = bias ? bias[col] : 0.f;
#pragma unroll
    for (int i = 0; i < MI; ++i) {
      const int rowb = m0 + wr + i * 16 + (lane >> 4) * 4;
#pragma unroll
      for (int rr = 0; rr < 4; ++rr) {
        float v = acc[i][j][rr] + bv;
        if (RELU) v = fmaxf(v, 0.f);
        if (WBF16) {
          const ushort_t hi = f2bf(v);
          const float lof = v - bf2f(hi);
          C[(long)(rowb + rr) * strideC + col]     = hi;
          C[(long)(rowb + rr) * strideC + N + col] = f2bf(lof);
        }
        if (WF32) { if (Cf) Cf[(long)(rowb + rr) * N + col] = v; }
      }
    }
  }
}

// ---------- fused GEMM3+GEMM4: eff = relu(relu(H2@W3+b3)@W4+b4) ----------
// Phase 1 = BK=32 4-deep pipelined GEMM (K=512, K''=1536) into acc; epilogue
// stores split H3 tile into the SAME 64KB LDS (8 chunk buffers [128][32]:
// hi c=0..3 -> SM[c], lo -> SM[4+c], XOR-swizzled). Phase 2 (K''=384):
// A-frags from LDS, B-frags straight from global W4t (L2-hot).
__global__ __launch_bounds__(256) void gemm34_k(
    const ushort_t* __restrict__ A, const ushort_t* __restrict__ W3t,
    const float* __restrict__ b3, const ushort_t* __restrict__ W4t,
    const float* __restrict__ b4, ushort_t* __restrict__ eff)
{
  __shared__ ushort_t SM[8][128 * 32];   // phase1: As=SM[0..3], Bs=SM[4..7]; phase2: H3 hi/lo

  const int tid  = threadIdx.x;
  const int lane = tid & 63;
  const int wave = tid >> 6;

  const int nwg  = gridDim.y;
  const int orig = blockIdx.y;
  const int xcd  = orig & 7;
  const int q    = nwg >> 3, r = nwg & 7;
  const int nid  = (xcd < r ? xcd * (q + 1) : r * (q + 1) + (xcd - r) * q) + (orig >> 3);
  const int m0   = nid * 128;

  const int wr = (wave >> 1) * 64;
  const int wc = (wave & 1) * 64;
  const int srow = tid >> 2;
  const int scol = (((tid & 3) ^ ((srow >> 1) & 3)) * 8);

  long aoff[2];
#pragma unroll
  for (int rr = 0; rr < 2; ++rr) aoff[rr] = (long)(m0 + rr * 64 + srow) * 1024 + scol;
  long boff[2];
#pragma unroll
  for (int rr = 0; rr < 2; ++rr) boff[rr] = (long)(rr * 64 + srow) * 1536 + scol;

  auto stage = [&](int kt, int b) {
    const int kpp = kt * 32;
    const int seg = (kpp >= 1024) ? 2 : ((kpp >= 512) ? 1 : 0);
    const int k   = kpp - seg * 512;
    const bool lop = (seg == 1);
#pragma unroll
    for (int rr = 0; rr < 2; ++rr)
      gload_lds16(A + aoff[rr] + (lop ? 512 : 0) + k, &SM[b][(rr * 64 + wave * 16) * 32]);
#pragma unroll
    for (int rr = 0; rr < 2; ++rr)
      gload_lds16(W3t + boff[rr] + kpp, &SM[4 + b][(rr * 64 + wave * 16) * 32]);
  };

  f32x4 zero = {0.f, 0.f, 0.f, 0.f};
  f32x4 acc[4][4];
#pragma unroll
  for (int i = 0; i < 4; ++i)
#pragma unroll
    for (int j = 0; j < 4; ++j) acc[i][j] = zero;

  stage(0, 0); stage(1, 1); stage(2, 2);

  for (int kt = 0; kt < 48; ++kt) {
    const int b = kt & 3;
    if (kt + 3 < 48) {
      stage(kt + 3, (kt + 3) & 3);
      asm volatile("s_waitcnt vmcnt(12)" ::: "memory");
    } else if (kt + 2 < 48) {
      asm volatile("s_waitcnt vmcnt(8)" ::: "memory");
    } else if (kt + 1 < 48) {
      asm volatile("s_waitcnt vmcnt(4)" ::: "memory");
    } else {
      asm volatile("s_waitcnt vmcnt(0)" ::: "memory");
    }
    __builtin_amdgcn_s_barrier();
    asm volatile("" ::: "memory");

    const int l15 = lane & 15;
    bf16x8 af[4];
#pragma unroll
    for (int i = 0; i < 4; ++i) {
      const int row = wr + i * 16 + l15;
      const int slot = (lane >> 4) ^ ((row >> 1) & 3);
      af[i] = *(const bf16x8*)&SM[b][row * 32 + slot * 8];
    }
#pragma unroll
    for (int jh = 0; jh < 2; ++jh) {
      bf16x8 bfr[2];
#pragma unroll
      for (int jj = 0; jj < 2; ++jj) {
        const int row = wc + (jh * 2 + jj) * 16 + l15;
        const int slot = (lane >> 4) ^ ((row >> 1) & 3);
        bfr[jj] = *(const bf16x8*)&SM[4 + b][row * 32 + slot * 8];
      }
      __builtin_amdgcn_s_setprio(1);
#pragma unroll
      for (int i = 0; i < 4; ++i)
#pragma unroll
        for (int jj = 0; jj < 2; ++jj)
          acc[i][jh * 2 + jj] =
              __builtin_amdgcn_mfma_f32_16x16x32_bf16(af[i], bfr[jj], acc[i][jh * 2 + jj], 0, 0, 0);
      __builtin_amdgcn_s_setprio(0);
    }

    asm volatile("" ::: "memory");
    __builtin_amdgcn_s_barrier();
    asm volatile("" ::: "memory");
  }

  // epilogue 1: relu(acc + b3) -> split H3 tile in LDS chunk buffers (swizzled)
#pragma unroll
  for (int j = 0; j < 4; ++j) {
    const int col = wc + j * 16 + (lane & 15);       // 0..127
    const float bv = b3[col];
    const int c = col >> 5, sl_lin = (col >> 3) & 3, e = col & 7;
#pragma unroll
    for (int i = 0; i < 4; ++i) {
      const int rowb = wr + i * 16 + (lane >> 4) * 4;
#pragma unroll
      for (int rr = 0; rr < 4; ++rr) {
        const int row = rowb + rr;
        float v = fmaxf(acc[i][j][rr] + bv, 0.f);
        const ushort_t hi = f2bf(v);
        const ushort_t lo = f2bf(v - bf2f(hi));
        const int slot = sl_lin ^ ((row >> 1) & 3);
        SM[c][row * 32 + slot * 8 + e]     = hi;
        SM[4 + c][row * 32 + slot * 8 + e] = lo;
      }
    }
  }
  asm volatile("s_waitcnt lgkmcnt(0)" ::: "memory");
  __builtin_amdgcn_sched_barrier(0);
  __builtin_amdgcn_s_barrier();
  asm volatile("" ::: "memory");

  // phase 2: eff_tile = relu(H3_tile @ W4 + b4). seg-major, chunk-ascending
  // (identical accumulation order to the unfused version).
  f32x4 acc2[4][4];
#pragma unroll
  for (int i = 0; i < 4; ++i)
#pragma unroll
    for (int j = 0; j < 4; ++j) acc2[i][j] = zero;

#pragma unroll
  for (int seg = 0; seg < 3; ++seg) {
#pragma unroll
    for (int c = 0; c < 4; ++c) {
      const int abuf = (seg == 1) ? (4 + c) : c;
      const int l15 = lane & 15;
      bf16x8 af[4];
#pragma unroll
      for (int i = 0; i < 4; ++i) {
        const int row = wr + i * 16 + l15;
        const int slot = (lane >> 4) ^ ((row >> 1) & 3);
        af[i] = *(const bf16x8*)&SM[abuf][row * 32 + slot * 8];
      }
#pragma unroll
      for (int jh = 0; jh < 2; ++jh) {
        bf16x8 bfr[2];
#pragma unroll
        for (int jj = 0; jj < 2; ++jj) {
          const int col2 = wc + (jh * 2 + jj) * 16 + l15;
          bfr[jj] = *(const bf16x8*)&W4t[(long)col2 * 384 + seg * 128 + c * 32 + (lane >> 4) * 8];
        }
        __builtin_amdgcn_s_setprio(1);
#pragma unroll
        for (int i = 0; i < 4; ++i)
#pragma unroll
          for (int jj = 0; jj < 2; ++jj)
            acc2[i][jh * 2 + jj] =
                __builtin_amdgcn_mfma_f32_16x16x32_bf16(af[i], bfr[jj], acc2[i][jh * 2 + jj], 0, 0, 0);
        __builtin_amdgcn_s_setprio(0);
      }
    }
  }

  // epilogue 2: relu(acc2 + b4) -> eff split [row][256]
#pragma unroll
  for (int j = 0; j < 4; ++j) {
    const int col = wc + j * 16 + (lane & 15);
    const float bv = b4[col];
#pragma unroll
    for (int i = 0; i < 4; ++i) {
      const int rowb = m0 + wr + i * 16 + (lane >> 4) * 4;
#pragma unroll
      for (int rr = 0; rr < 4; ++rr) {
        float v = fmaxf(acc2[i][j][rr] + bv, 0.f);
        const ushort_t hi = f2bf(v);
        eff[(long)(rowb + rr) * 256 + col]       = hi;
        eff[(long)(rowb + rr) * 256 + 128 + col] = f2bf(v - bf2f(hi));
      }
    }
  }
}

// ---------- helpers ----------
__global__ void cvt_split_k(const float* __restrict__ x, ushort_t* __restrict__ y,
                            int total, int W) {
  int i = blockIdx.x * 256 + threadIdx.x;
  if (i >= total) return;
  int row = i / W, k = i - row * W;
  float v = x[i];
  ushort_t hi = f2bf(v);
  float lof = v - bf2f(hi);
  y[(long)row * (2 * W) + k]     = hi;
  y[(long)row * (2 * W) + W + k] = f2bf(lof);
}

// W[K][N] f32 -> Bt[n][3K] bf16 = [hi | hi | lo]
__global__ void transpose_cvt_split_k(const float* __restrict__ W, ushort_t* __restrict__ Bt,
                                      int K, int N) {
  int idx = blockIdx.x * 256 + threadIdx.x;
  if (idx >= K * N) return;
  int k = idx / N, n = idx - k * N;
  float v = W[idx];
  ushort_t hi = f2bf(v);
  float lof = v - bf2f(hi);
  ushort_t lo = f2bf(lof);
  long base = (long)n * (3 * K);
  Bt[base + k]         = hi;
  Bt[base + K + k]     = hi;
  Bt[base + 2 * K + k] = lo;
}

// Wr1 [1024][512] f32 -> WUVt [1024][1536]
__global__ void tr_uv_k(const float* __restrict__ W, ushort_t* __restrict__ Bt) {
  int idx = blockIdx.x * 256 + threadIdx.x;
  if (idx >= 1024 * 512) return;
  int n = idx >> 9, k = idx & 511;
  float v = (n < 512) ? W[(long)k * 512 + n] : W[(long)(512 + k) * 512 + (n - 512)];
  ushort_t hi = f2bf(v);
  float lof = v - bf2f(hi);
  long base = (long)n * 1536;
  Bt[base + k]        = hi;
  Bt[base + 512 + k]  = hi;
  Bt[base + 1024 + k] = f2bf(lof);
}

__global__ void tables_k(int* __restrict__ srcN, int* __restrict__ dstN) {
  int m = blockIdx.x * 256 + threadIdx.x;
  if (m >= MROWS) return;
  int b = m / NREL_;
  int e = m - b * NREL_;
  int i = e / 31;
  int jj = e - i * 31;
  int j = jj + (jj >= i ? 1 : 0);
  srcN[m] = b * N_ + i;
  dstN[m] = b * N_ + j;
}

__global__ __launch_bounds__(256) void assemble_h1_k(
    const float* __restrict__ UV, const int* __restrict__ srcN,
    const int* __restrict__ dstN, const float* __restrict__ br1,
    ushort_t* __restrict__ H1c, long r0) {
  const int rlocal = blockIdx.x * 2 + (threadIdx.x >> 7);
  const long m = r0 + rlocal;
  const int k0 = (threadIdx.x & 127) * 4;
  const float4 u  = *(const float4*)&UV[(long)srcN[m] * 1024 + k0];
  const float4 w  = *(const float4*)&UV[(long)dstN[m] * 1024 + 512 + k0];
  const float4 bv = *(const float4*)&br1[k0];
  float v0 = fmaxf(u.x + w.x + bv.x, 0.f);
  float v1 = fmaxf(u.y + w.y + bv.y, 0.f);
  float v2 = fmaxf(u.z + w.z + bv.z, 0.f);
  float v3 = fmaxf(u.w + w.w + bv.w, 0.f);
  ushort4 hi, lo;
  hi.x = f2bf(v0); lo.x = f2bf(v0 - bf2f(hi.x));
  hi.y = f2bf(v1); lo.y = f2bf(v1 - bf2f(hi.y));
  hi.z = f2bf(v2); lo.z = f2bf(v2 - bf2f(hi.z));
  hi.w = f2bf(v3); lo.w = f2bf(v3 - bf2f(hi.w));
  *(ushort4*)&H1c[(long)rlocal * 1024 + k0]       = hi;
  *(ushort4*)&H1c[(long)rlocal * 1024 + 512 + k0] = lo;
}

__global__ void scatter_k(const ushort_t* __restrict__ eff, ushort_t* __restrict__ agg) {
  int bn = blockIdx.x;
  int b = bn >> 5, n = bn & 31, f = threadIdx.x;   // 128 threads = E_
  float s = 0.f;
#pragma unroll
  for (int i = 0; i < N_; ++i) {
    if (i == n) continue;
    int jj = (n < i) ? n : (n - 1);
    int e = i * 31 + jj;
    long base = ((long)b * NREL_ + e) * 256;
    s += bf2f(eff[base + f]) + bf2f(eff[base + 128 + f]);
  }
  long obase = ((long)b * N_ + n) * 256;
  ushort_t hi = f2bf(s);
  agg[obase + f]       = hi;
  agg[obase + 128 + f] = f2bf(s - bf2f(hi));
}

__global__ void head_k(const ushort_t* __restrict__ ent, const float* __restrict__ Wl,
                       const float* __restrict__ bl, float* __restrict__ out, int t) {
  int b = blockIdx.x >> 2, n = blockIdx.x & 3, lane = threadIdx.x;   // 64 threads
  const ushort_t* e = ent + (long)(b * N_ + n) * 1024;
  float a0 = 0.f, a1 = 0.f;
  for (int k = lane; k < D_; k += 64) {
    float v = bf2f(e[k]) + bf2f(e[512 + k]);
    a0 += v * Wl[2 * k]; a1 += v * Wl[2 * k + 1];
  }
#pragma unroll
  for (int s = 32; s > 0; s >>= 1) { a0 += __shfl_down(a0, s); a1 += __shfl_down(a1, s); }
  if (lane == 0) {
    out[((long)b * T_ + t) * 8 + n * 2 + 0] = a0 + bl[0];
    out[((long)b * T_ + t) * 8 + n * 2 + 1] = a1 + bl[1];
  }
}

// ---------- launch ----------
extern "C" void kernel_launch(void* const* d_in, const int* in_sizes, int n_in,
                              void* d_out, int out_size, void* d_ws, size_t ws_size,
                              hipStream_t stream) {
  const float* entity = (const float*)d_in[0];
  const float* Wr1 = (const float*)d_in[3];  const float* br1 = (const float*)d_in[4];
  const float* Wr2 = (const float*)d_in[5];  const float* br2 = (const float*)d_in[6];
  const float* Wr3 = (const float*)d_in[7];  const float* br3 = (const float*)d_in[8];
  const float* Wr4 = (const float*)d_in[9];  const float* br4 = (const float*)d_in[10];
  const float* Wo1 = (const float*)d_in[11]; const float* bo1 = (const float*)d_in[12];
  const float* Wo2 = (const float*)d_in[13]; const float* bo2 = (const float*)d_in[14];
  const float* Wl  = (const float*)d_in[15]; const float* bl  = (const float*)d_in[16];

  const size_t fixedBytes = (size_t)70 * 1024 * 1024;
  int nchunk = 4;
  for (int c = 1; c <= 4; c *= 2) {
    size_t tot = fixedBytes + 2 * ((size_t)(MROWS / c) * 1024 * 2);
    if (tot <= ws_size) { nchunk = c; break; }
  }
  const int CH = MROWS / nchunk;

  char* ws = (char*)d_ws;
  size_t off = 0;
  auto alloc = [&](size_t bytes) -> void* {
    void* p = ws + off; off = (off + bytes + 255) & ~(size_t)255; return p;
  };
  ushort_t* entP0 = (ushort_t*)alloc((size_t)MOBJ * 1024 * 2);
  ushort_t* entP1 = (ushort_t*)alloc((size_t)MOBJ * 1024 * 2);
  float* UV = (float*)alloc((size_t)MOBJ * 1024 * 4);
  ushort_t* eff = (ushort_t*)alloc((size_t)MROWS * 256 * 2);
  ushort_t* agg = (ushort_t*)alloc((size_t)MOBJ * 256 * 2);
  ushort_t* G   = (ushort_t*)alloc((size_t)MOBJ * 1024 * 2);
  ushort_t* WUVt = (ushort_t*)alloc((size_t)1024 * 1536 * 2);
  ushort_t* Wr2t = (ushort_t*)alloc((size_t)512 * 1536 * 2);
  ushort_t* Wr3t = (ushort_t*)alloc((size_t)128 * 1536 * 2);
  ushort_t* Wr4t = (ushort_t*)alloc((size_t)128 * 384 * 2);
  ushort_t* Wo1t = (ushort_t*)alloc((size_t)512 * 1920 * 2);
  ushort_t* Wo2t = (ushort_t*)alloc((size_t)512 * 1536 * 2);
  int* srcN = (int*)alloc((size_t)MROWS * 4);
  int* dstN = (int*)alloc((size_t)MROWS * 4);
  ushort_t* H1c = (ushort_t*)alloc((size_t)CH * 1024 * 2);
  ushort_t* H2c = (ushort_t*)alloc((size_t)CH * 1024 * 2);
  (void)in_sizes; (void)n_in; (void)out_size;

  tr_uv_k<<<(1024 * 512 + 255) / 256, 256, 0, stream>>>(Wr1, WUVt);
  transpose_cvt_split_k<<<(512 * 512 + 255) / 256, 256, 0, stream>>>(Wr2, Wr2t, 512, 512);
  transpose_cvt_split_k<<<(512 * 128 + 255) / 256, 256, 0, stream>>>(Wr3, Wr3t, 512, 128);
  transpose_cvt_split_k<<<(128 * 128 + 255) / 256, 256, 0, stream>>>(Wr4, Wr4t, 128, 128);
  transpose_cvt_split_k<<<(640 * 512 + 255) / 256, 256, 0, stream>>>(Wo1, Wo1t, 640, 512);
  transpose_cvt_split_k<<<(512 * 512 + 255) / 256, 256, 0, stream>>>(Wo2, Wo2t, 512, 512);
  tables_k<<<(MROWS + 255) / 256, 256, 0, stream>>>(srcN, dstN);
  cvt_split_k<<<(MOBJ * D_ + 255) / 256, 256, 0, stream>>>(entity, entP0, MOBJ * D_, D_);

  float* outP    = (float*)d_out;
  float* lastEnt = outP + (size_t)B_ * T_ * 8;

  ushort_t* cur = entP0;
  ushort_t* nxt = entP1;
  for (int t = 0; t < T_; ++t) {
    // UV = ent @ [Wr1_top | Wr1_bot]  (f32 out)  [2048 x 1024], TM=64 -> 256 blocks
    gemm_k<0, false, false, true, 64><<<dim3(8, MOBJ / 64), 256, 0, stream>>>(
        cur, nullptr, WUVt, nullptr, nullptr, UV, MOBJ, 1024, 512);

    for (int c = 0; c < nchunk; ++c) {
      const long r0 = (long)c * CH;
      assemble_h1_k<<<CH / 2, 256, 0, stream>>>(UV, srcN, dstN, br1, H1c, r0);
      // GEMM2: H1c @ Wr2 -> H2c, relu
      gemm_k<0, true, true, false, 128><<<dim3(4, CH / 128), 256, 0, stream>>>(
          H1c, nullptr, Wr2t, br2, H2c, nullptr, CH, 512, 512);
      // fused GEMM3+GEMM4: H2c -> eff chunk
      gemm34_k<<<dim3(1, CH / 128), 256, 0, stream>>>(
          H2c, Wr3t, br3, Wr4t, br4, eff + r0 * 256);
    }
    scatter_k<<<MOBJ, 128, 0, stream>>>(eff, agg);
    // GEMM5: concat(ent, agg) [2048,640] @ Wo1 -> G, relu  (TM=64 -> 128 blocks)
    gemm_k<2, true, true, false, 64><<<dim3(4, MOBJ / 64), 256, 0, stream>>>(
        cur, agg, Wo1t, bo1, G, nullptr, MOBJ, 512, 640);
    // GEMM6: G @ Wo2 -> new entity (+ f32 last_entity on final step)
    float* cf = (t == T_ - 1) ? lastEnt : nullptr;
    gemm_k<0, false, true, true, 64><<<dim3(4, MOBJ / 64), 256, 0, stream>>>(
        G, nullptr, Wo2t, bo2, nxt, cf, MOBJ, 512, 512);
    head_k<<<256, 64, 0, stream>>>(nxt, Wl, bl, outP, t);

    ushort_t* tmp = cur; cur = nxt; nxt = tmp;
  }
}

// Round 8
// 5078.599 us; speedup vs baseline: 1.1766x; 1.1766x over previous
//
#include <hip/hip_runtime.h>
#include <stdint.h>
#include <stddef.h>

// ---------- constants ----------
#define B_    64
#define N_    32
#define NREL_ 992
#define D_    512
#define E_    128
#define H_    512
#define T_    16
#define MROWS (B_ * NREL_)   // 63488
#define MOBJ  (B_ * N_)      // 2048

typedef unsigned short ushort_t;
typedef __attribute__((ext_vector_type(8))) short bf16x8;   // 8 bf16 = 4 VGPRs (MFMA A/B frag)
typedef __attribute__((ext_vector_type(4))) float f32x4;    // MFMA C/D frag

typedef __attribute__((address_space(1))) const void gvoid;
typedef __attribute__((address_space(3))) void lvoid;

__device__ __forceinline__ float bf2f(ushort_t u) {
  union { unsigned int i; float f; } v; v.i = ((unsigned int)u) << 16; return v.f;
}
__device__ __forceinline__ ushort_t f2bf(float f) {   // round-to-nearest-even
  union { float f; unsigned int i; } v; v.f = f;
  unsigned int u = v.i;
  u += 0x7FFFu + ((u >> 16) & 1u);
  return (ushort_t)(u >> 16);
}
__device__ __forceinline__ void gload_lds16(const void* g, void* l) {
  __builtin_amdgcn_global_load_lds((gvoid*)g, (lvoid*)l, 16, 0, 0);
}

// ---------- TMxTN MFMA GEMM, 3xBF16 fp32 emulation (R6 structure) ----------
// BK=64, double-buffered LDS, counted vmcnt (= loads of one tile), raw
// s_barrier, setprio(1) around MFMA clusters, XOR bank-swizzle applied as
// pre-swizzled global SOURCE (linear gload_lds dest) + swizzled ds_read addr.
// MODE 0: A rows plain split [M][2K] = [hi K | lo K].
// MODE 2: logical row m = concat(ent[m](512), agg[m](128)); K=640.
template<int MODE, bool RELU, bool WBF16, bool WF32, int TM, int TN>
__global__ __launch_bounds__(256) void gemm_k(
    const ushort_t* __restrict__ A, const ushort_t* __restrict__ A2,
    const ushort_t* __restrict__ Bt, const float* __restrict__ bias,
    ushort_t* __restrict__ C, float* __restrict__ Cf,
    int M, int N, int K)
{
  constexpr int MI = TM / 32;          // A frags per wave = A staging rounds
  constexpr int NB = TN / 32;          // B staging rounds
  constexpr int NJ = TN / 32;          // B frags per wave
  __shared__ ushort_t As[2][TM * 64];
  __shared__ ushort_t Bs[2][TN * 64];

  const int tid  = threadIdx.x;
  const int lane = tid & 63;
  const int wave = tid >> 6;

  // bijective XCD-chunked tile remap (m204)
  const int nwg  = gridDim.x * gridDim.y;
  const int orig = blockIdx.y * gridDim.x + blockIdx.x;
  const int xcd  = orig & 7;
  const int q    = nwg >> 3, r = nwg & 7;
  const int nid  = (xcd < r ? xcd * (q + 1) : r * (q + 1) + (xcd - r) * q) + (orig >> 3);
  const int m0 = (nid / gridDim.x) * TM;
  const int n0 = (nid % gridDim.x) * TN;

  const int wr = (wave >> 1) * (TM / 2);
  const int wc = (wave & 1) * (TN / 2);

  const int srow = tid >> 3;          // 0..31: staging row within a 32-row round
  const int scol = (((tid & 7) ^ (srow & 7)) * 8);    // swizzled source col (elements)

  long aoff[MI]; long aoff2[MI];
#pragma unroll
  for (int rr = 0; rr < MI; ++rr) {
    int m = m0 + rr * 32 + srow;
    if (MODE == 0) { aoff[rr] = (long)m * (2 * K) + scol; aoff2[rr] = 0; }
    else           { aoff[rr] = (long)m * 1024 + scol; aoff2[rr] = (long)m * 256 + scol; }
  }
  long boff[NB];
#pragma unroll
  for (int rr = 0; rr < NB; ++rr) boff[rr] = (long)(n0 + rr * 32 + srow) * (3 * K) + scol;

  const int NT = (3 * K) >> 6;   // K-tiles of 64

  auto stage = [&](int kt, int b) {
    const int kpp = kt * 64;
    const int seg = (kpp >= 2 * K) ? 2 : ((kpp >= K) ? 1 : 0);
    const int k   = kpp - seg * K;
    const bool lop = (seg == 1);
#pragma unroll
    for (int rr = 0; rr < MI; ++rr) {
      const ushort_t* src;
      if (MODE == 0) {
        src = A + aoff[rr] + (lop ? K : 0) + k;
      } else {
        if (k < 512) src = A  + aoff[rr]  + (lop ? 512 : 0) + k;
        else         src = A2 + aoff2[rr] + (lop ? 128 : 0) + (k - 512);
      }
      gload_lds16(src, &As[b][(rr * 32 + wave * 8) * 64]);
    }
#pragma unroll
    for (int rr = 0; rr < NB; ++rr)
      gload_lds16(Bt + boff[rr] + kpp, &Bs[b][(rr * 32 + wave * 8) * 64]);
  };

  f32x4 zero = {0.f, 0.f, 0.f, 0.f};
  f32x4 acc[MI][NJ];
#pragma unroll
  for (int i = 0; i < MI; ++i)
#pragma unroll
    for (int j = 0; j < NJ; ++j) acc[i][j] = zero;

  stage(0, 0);
  if (NT > 1) stage(1, 1);

  for (int kt = 0; kt < NT; ++kt) {
    const int b = kt & 1;
    if (kt + 1 < NT) {
      if constexpr (MI + NB == 8)      asm volatile("s_waitcnt vmcnt(8)" ::: "memory");
      else if constexpr (MI + NB == 6) asm volatile("s_waitcnt vmcnt(6)" ::: "memory");
      else                             asm volatile("s_waitcnt vmcnt(4)" ::: "memory");
    } else {
      asm volatile("s_waitcnt vmcnt(0)" ::: "memory");
    }
    __builtin_amdgcn_s_barrier();
    asm volatile("" ::: "memory");

#pragma unroll
    for (int kk = 0; kk < 2; ++kk) {
      const int cel = (((kk * 4 + (lane >> 4)) ^ (lane & 7)) << 3);
      bf16x8 af[MI];
#pragma unroll
      for (int i = 0; i < MI; ++i)
        af[i] = *(const bf16x8*)&As[b][(wr + i * 16 + (lane & 15)) * 64 + cel];
#pragma unroll
      for (int jh = 0; jh < NJ / 2; ++jh) {
        bf16x8 bfr[2];
#pragma unroll
        for (int jj = 0; jj < 2; ++jj)
          bfr[jj] = *(const bf16x8*)&Bs[b][(wc + (jh * 2 + jj) * 16 + (lane & 15)) * 64 + cel];
        __builtin_amdgcn_s_setprio(1);
#pragma unroll
        for (int i = 0; i < MI; ++i)
#pragma unroll
          for (int jj = 0; jj < 2; ++jj)
            acc[i][jh * 2 + jj] =
                __builtin_amdgcn_mfma_f32_16x16x32_bf16(af[i], bfr[jj], acc[i][jh * 2 + jj], 0, 0, 0);
        __builtin_amdgcn_s_setprio(0);
      }
    }

    asm volatile("" ::: "memory");
    __builtin_amdgcn_s_barrier();
    asm volatile("" ::: "memory");
    if (kt + 2 < NT) stage(kt + 2, b);
  }

  const long strideC = 2 * (long)N;
#pragma unroll
  for (int j = 0; j < NJ; ++j) {
    const int col = n0 + wc + j * 16 + (lane & 15);
    const float bv = bias ? bias[col] : 0.f;
#pragma unroll
    for (int i = 0; i < MI; ++i) {
      const int rowb = m0 + wr + i * 16 + (lane >> 4) * 4;
#pragma unroll
      for (int rr = 0; rr < 4; ++rr) {
        float v = acc[i][j][rr] + bv;
        if (RELU) v = fmaxf(v, 0.f);
        if (WBF16) {
          const ushort_t hi = f2bf(v);
          const float lof = v - bf2f(hi);
          C[(long)(rowb + rr) * strideC + col]     = hi;
          C[(long)(rowb + rr) * strideC + N + col] = f2bf(lof);
        }
        if (WF32) { if (Cf) Cf[(long)(rowb + rr) * N + col] = v; }
      }
    }
  }
}

// ---------- GEMM2 specialized: 256x256 tile, 8 waves (512 thr), 128KB LDS ----------
// H2c = relu(H1c @ Wr2 + br2); M rows (mult of 256), N=512, K=512, K''=1536.
// Wave owns 128x64 output (MI=8, NJ=4): 24 ds_read_b128 per 64 MFMA per K-tile
// (384 B/MFMA, LDS-feed ceiling ~91% of MFMA peak vs 69% at 128x128).
// Same R6 sync discipline: 2 buffers, stage after bar2, vmcnt(8), drain at end.
__global__ __launch_bounds__(512) void gemm2_256_k(
    const ushort_t* __restrict__ A,   // H1c split [M][1024]
    const ushort_t* __restrict__ Bt,  // Wr2t [512][1536]
    const float* __restrict__ bias,
    ushort_t* __restrict__ C,         // H2c split [M][1024]
    int M)
{
  __shared__ ushort_t As[2][256 * 64];   // 32KB x2
  __shared__ ushort_t Bs[2][256 * 64];   // 32KB x2

  const int tid  = threadIdx.x;
  const int lane = tid & 63;
  const int wave = tid >> 6;          // 0..7

  const int nwg  = gridDim.x * gridDim.y;
  const int orig = blockIdx.y * gridDim.x + blockIdx.x;
  const int xcd  = orig & 7;
  const int q    = nwg >> 3, r = nwg & 7;
  const int nid  = (xcd < r ? xcd * (q + 1) : r * (q + 1) + (xcd - r) * q) + (orig >> 3);
  const int m0 = (nid / gridDim.x) * 256;
  const int n0 = (nid % gridDim.x) * 256;

  const int wr = (wave >> 2) * 128;   // 0 or 128
  const int wc = (wave & 3) * 64;     // 0,64,128,192

  const int srow = tid >> 3;          // 0..63: staging row within a 64-row round
  const int scol = (((tid & 7) ^ (srow & 7)) * 8);

  long aoff[4];
#pragma unroll
  for (int rr = 0; rr < 4; ++rr) aoff[rr] = (long)(m0 + rr * 64 + srow) * 1024 + scol;
  long boff[4];
#pragma unroll
  for (int rr = 0; rr < 4; ++rr) boff[rr] = (long)(n0 + rr * 64 + srow) * 1536 + scol;

  auto stage = [&](int kt, int b) {
    const int kpp = kt * 64;
    const int seg = (kpp >= 1024) ? 2 : ((kpp >= 512) ? 1 : 0);
    const int k   = kpp - seg * 512;
    const bool lop = (seg == 1);
#pragma unroll
    for (int rr = 0; rr < 4; ++rr)
      gload_lds16(A + aoff[rr] + (lop ? 512 : 0) + k, &As[b][(rr * 64 + wave * 8) * 64]);
#pragma unroll
    for (int rr = 0; rr < 4; ++rr)
      gload_lds16(Bt + boff[rr] + kpp, &Bs[b][(rr * 64 + wave * 8) * 64]);
  };

  f32x4 zero = {0.f, 0.f, 0.f, 0.f};
  f32x4 acc[8][4];
#pragma unroll
  for (int i = 0; i < 8; ++i)
#pragma unroll
    for (int j = 0; j < 4; ++j) acc[i][j] = zero;

  stage(0, 0);
  stage(1, 1);

  for (int kt = 0; kt < 24; ++kt) {
    const int b = kt & 1;
    if (kt + 1 < 24) asm volatile("s_waitcnt vmcnt(8)" ::: "memory");
    else             asm volatile("s_waitcnt vmcnt(0)" ::: "memory");
    __builtin_amdgcn_s_barrier();
    asm volatile("" ::: "memory");

#pragma unroll
    for (int kk = 0; kk < 2; ++kk) {
      const int cel = (((kk * 4 + (lane >> 4)) ^ (lane & 7)) << 3);
      bf16x8 af[8];
#pragma unroll
      for (int i = 0; i < 8; ++i)
        af[i] = *(const bf16x8*)&As[b][(wr + i * 16 + (lane & 15)) * 64 + cel];
      bf16x8 bfr[4];
#pragma unroll
      for (int j = 0; j < 4; ++j)
        bfr[j] = *(const bf16x8*)&Bs[b][(wc + j * 16 + (lane & 15)) * 64 + cel];
      __builtin_amdgcn_s_setprio(1);
#pragma unroll
      for (int i = 0; i < 8; ++i)
#pragma unroll
        for (int j = 0; j < 4; ++j)
          acc[i][j] = __builtin_amdgcn_mfma_f32_16x16x32_bf16(af[i], bfr[j], acc[i][j], 0, 0, 0);
      __builtin_amdgcn_s_setprio(0);
    }

    asm volatile("" ::: "memory");
    __builtin_amdgcn_s_barrier();
    asm volatile("" ::: "memory");
    if (kt + 2 < 24) stage(kt + 2, b);
  }

  // epilogue: relu(acc + bias) -> H2c split [row][1024] = [hi512 | lo512]
#pragma unroll
  for (int j = 0; j < 4; ++j) {
    const int col = n0 + wc + j * 16 + (lane & 15);
    const float bv = bias[col];
#pragma unroll
    for (int i = 0; i < 8; ++i) {
      const int rowb = m0 + wr + i * 16 + (lane >> 4) * 4;
#pragma unroll
      for (int rr = 0; rr < 4; ++rr) {
        float v = fmaxf(acc[i][j][rr] + bv, 0.f);
        const ushort_t hi = f2bf(v);
        C[(long)(rowb + rr) * 1024 + col]       = hi;
        C[(long)(rowb + rr) * 1024 + 512 + col] = f2bf(v - bf2f(hi));
      }
    }
  }
}

// ---------- fused GEMM3+GEMM4 (R6 form): eff = relu(relu(H2@W3+b3)@W4+b4) ----------
__global__ __launch_bounds__(256) void gemm34_k(
    const ushort_t* __restrict__ A, const ushort_t* __restrict__ W3t,
    const float* __restrict__ b3, const ushort_t* __restrict__ W4t,
    const float* __restrict__ b4, ushort_t* __restrict__ eff)
{
  __shared__ ushort_t SM[4][128 * 64];   // phase1: As0,As1,Bs0,Bs1; phase2: H3 hi0,hi1,lo0,lo1
  ushort_t* SMf = &SM[0][0];

  const int tid  = threadIdx.x;
  const int lane = tid & 63;
  const int wave = tid >> 6;

  const int nwg  = gridDim.y;
  const int orig = blockIdx.y;
  const int xcd  = orig & 7;
  const int q    = nwg >> 3, r = nwg & 7;
  const int nid  = (xcd < r ? xcd * (q + 1) : r * (q + 1) + (xcd - r) * q) + (orig >> 3);
  const int m0   = nid * 128;

  const int wr = (wave >> 1) * 64;
  const int wc = (wave & 1) * 64;
  const int srow = tid >> 3;
  const int scol = (((tid & 7) ^ (srow & 7)) * 8);

  long aoff[4];
#pragma unroll
  for (int rr = 0; rr < 4; ++rr) aoff[rr] = (long)(m0 + rr * 32 + srow) * 1024 + scol;
  long boff[4];
#pragma unroll
  for (int rr = 0; rr < 4; ++rr) boff[rr] = (long)(rr * 32 + srow) * 1536 + scol;

  auto stage = [&](int kt, int b) {
    const int kpp = kt * 64;
    const int seg = (kpp >= 1024) ? 2 : ((kpp >= 512) ? 1 : 0);
    const int k   = kpp - seg * 512;
    const bool lop = (seg == 1);
#pragma unroll
    for (int rr = 0; rr < 4; ++rr)
      gload_lds16(A + aoff[rr] + (lop ? 512 : 0) + k, &SM[b][(rr * 32 + wave * 8) * 64]);
#pragma unroll
    for (int rr = 0; rr < 4; ++rr)
      gload_lds16(W3t + boff[rr] + kpp, &SM[2 + b][(rr * 32 + wave * 8) * 64]);
  };

  f32x4 zero = {0.f, 0.f, 0.f, 0.f};
  f32x4 acc[4][4];
#pragma unroll
  for (int i = 0; i < 4; ++i)
#pragma unroll
    for (int j = 0; j < 4; ++j) acc[i][j] = zero;

  stage(0, 0);
  stage(1, 1);

  for (int kt = 0; kt < 24; ++kt) {
    const int b = kt & 1;
    if (kt + 1 < 24) asm volatile("s_waitcnt vmcnt(8)" ::: "memory");
    else             asm volatile("s_waitcnt vmcnt(0)" ::: "memory");
    __builtin_amdgcn_s_barrier();
    asm volatile("" ::: "memory");

#pragma unroll
    for (int kk = 0; kk < 2; ++kk) {
      const int cel = (((kk * 4 + (lane >> 4)) ^ (lane & 7)) << 3);
      bf16x8 af[4];
#pragma unroll
      for (int i = 0; i < 4; ++i)
        af[i] = *(const bf16x8*)&SM[b][(wr + i * 16 + (lane & 15)) * 64 + cel];
#pragma unroll
      for (int jh = 0; jh < 2; ++jh) {
        bf16x8 bfr[2];
#pragma unroll
        for (int jj = 0; jj < 2; ++jj)
          bfr[jj] = *(const bf16x8*)&SM[2 + b][(wc + (jh * 2 + jj) * 16 + (lane & 15)) * 64 + cel];
        __builtin_amdgcn_s_setprio(1);
#pragma unroll
        for (int i = 0; i < 4; ++i)
#pragma unroll
          for (int jj = 0; jj < 2; ++jj)
            acc[i][jh * 2 + jj] =
                __builtin_amdgcn_mfma_f32_16x16x32_bf16(af[i], bfr[jj], acc[i][jh * 2 + jj], 0, 0, 0);
        __builtin_amdgcn_s_setprio(0);
      }
    }

    asm volatile("" ::: "memory");
    __builtin_amdgcn_s_barrier();
    asm volatile("" ::: "memory");
    if (kt + 2 < 24) stage(kt + 2, b);
  }

  // epilogue 1: relu(acc + b3) -> split H3 tile in LDS (swizzled subtiles)
#pragma unroll
  for (int j = 0; j < 4; ++j) {
    const int col = wc + j * 16 + (lane & 15);       // 0..127
    const float bv = b3[col];
    const int thi = col >> 6, c = col & 63;
#pragma unroll
    for (int i = 0; i < 4; ++i) {
      const int rowb = wr + i * 16 + (lane >> 4) * 4;
#pragma unroll
      for (int rr = 0; rr < 4; ++rr) {
        const int row = rowb + rr;
        float v = fmaxf(acc[i][j][rr] + bv, 0.f);
        const ushort_t hi = f2bf(v);
        const ushort_t lo = f2bf(v - bf2f(hi));
        const int slot = ((c >> 3) ^ (row & 7)) * 8 + (c & 7);
        SMf[(thi * 128 + row) * 64 + slot]       = hi;
        SMf[((2 + thi) * 128 + row) * 64 + slot] = lo;
      }
    }
  }
  asm volatile("s_waitcnt lgkmcnt(0)" ::: "memory");
  __builtin_amdgcn_sched_barrier(0);
  __builtin_amdgcn_s_barrier();
  asm volatile("" ::: "memory");

  // phase 2: eff_tile = relu(H3_tile @ W4 + b4). A-tiles kt2: 0,1=hi 2,3=lo 4,5=hi.
  f32x4 acc2[4][4];
#pragma unroll
  for (int i = 0; i < 4; ++i)
#pragma unroll
    for (int j = 0; j < 4; ++j) acc2[i][j] = zero;

#pragma unroll
  for (int kt2 = 0; kt2 < 6; ++kt2) {
    const int phys = kt2 & 3;
#pragma unroll
    for (int kk = 0; kk < 2; ++kk) {
      const int cel = (((kk * 4 + (lane >> 4)) ^ (lane & 7)) << 3);
      bf16x8 af[4];
#pragma unroll
      for (int i = 0; i < 4; ++i)
        af[i] = *(const bf16x8*)&SMf[(phys * 128 + wr + i * 16 + (lane & 15)) * 64 + cel];
#pragma unroll
      for (int jh = 0; jh < 2; ++jh) {
        bf16x8 bfr[2];
#pragma unroll
        for (int jj = 0; jj < 2; ++jj) {
          const int col2 = wc + (jh * 2 + jj) * 16 + (lane & 15);
          bfr[jj] = *(const bf16x8*)&W4t[(long)col2 * 384 + kt2 * 64 + kk * 32 + (lane >> 4) * 8];
        }
        __builtin_amdgcn_s_setprio(1);
#pragma unroll
        for (int i = 0; i < 4; ++i)
#pragma unroll
          for (int jj = 0; jj < 2; ++jj)
            acc2[i][jh * 2 + jj] =
                __builtin_amdgcn_mfma_f32_16x16x32_bf16(af[i], bfr[jj], acc2[i][jh * 2 + jj], 0, 0, 0);
        __builtin_amdgcn_s_setprio(0);
      }
    }
  }

  // epilogue 2: relu(acc2 + b4) -> eff split [row][256]
#pragma unroll
  for (int j = 0; j < 4; ++j) {
    const int col = wc + j * 16 + (lane & 15);
    const float bv = b4[col];
#pragma unroll
    for (int i = 0; i < 4; ++i) {
      const int rowb = m0 + wr + i * 16 + (lane >> 4) * 4;
#pragma unroll
      for (int rr = 0; rr < 4; ++rr) {
        float v = fmaxf(acc2[i][j][rr] + bv, 0.f);
        const ushort_t hi = f2bf(v);
        eff[(long)(rowb + rr) * 256 + col]       = hi;
        eff[(long)(rowb + rr) * 256 + 128 + col] = f2bf(v - bf2f(hi));
      }
    }
  }
}

// ---------- helpers ----------
__global__ void cvt_split_k(const float* __restrict__ x, ushort_t* __restrict__ y,
                            int total, int W) {
  int i = blockIdx.x * 256 + threadIdx.x;
  if (i >= total) return;
  int row = i / W, k = i - row * W;
  float v = x[i];
  ushort_t hi = f2bf(v);
  float lof = v - bf2f(hi);
  y[(long)row * (2 * W) + k]     = hi;
  y[(long)row * (2 * W) + W + k] = f2bf(lof);
}

__global__ void transpose_cvt_split_k(const float* __restrict__ W, ushort_t* __restrict__ Bt,
                                      int K, int N) {
  int idx = blockIdx.x * 256 + threadIdx.x;
  if (idx >= K * N) return;
  int k = idx / N, n = idx - k * N;
  float v = W[idx];
  ushort_t hi = f2bf(v);
  float lof = v - bf2f(hi);
  ushort_t lo = f2bf(lof);
  long base = (long)n * (3 * K);
  Bt[base + k]         = hi;
  Bt[base + K + k]     = hi;
  Bt[base + 2 * K + k] = lo;
}

__global__ void tr_uv_k(const float* __restrict__ W, ushort_t* __restrict__ Bt) {
  int idx = blockIdx.x * 256 + threadIdx.x;
  if (idx >= 1024 * 512) return;
  int n = idx >> 9, k = idx & 511;
  float v = (n < 512) ? W[(long)k * 512 + n] : W[(long)(512 + k) * 512 + (n - 512)];
  ushort_t hi = f2bf(v);
  float lof = v - bf2f(hi);
  long base = (long)n * 1536;
  Bt[base + k]        = hi;
  Bt[base + 512 + k]  = hi;
  Bt[base + 1024 + k] = f2bf(lof);
}

__global__ void tables_k(int* __restrict__ srcN, int* __restrict__ dstN) {
  int m = blockIdx.x * 256 + threadIdx.x;
  if (m >= MROWS) return;
  int b = m / NREL_;
  int e = m - b * NREL_;
  int i = e / 31;
  int jj = e - i * 31;
  int j = jj + (jj >= i ? 1 : 0);
  srcN[m] = b * N_ + i;
  dstN[m] = b * N_ + j;
}

__global__ __launch_bounds__(256) void assemble_h1_k(
    const float* __restrict__ UV, const int* __restrict__ srcN,
    const int* __restrict__ dstN, const float* __restrict__ br1,
    ushort_t* __restrict__ H1c, long r0) {
  const int rlocal = blockIdx.x * 2 + (threadIdx.x >> 7);
  const long m = r0 + rlocal;
  const int k0 = (threadIdx.x & 127) * 4;
  const float4 u  = *(const float4*)&UV[(long)srcN[m] * 1024 + k0];
  const float4 w  = *(const float4*)&UV[(long)dstN[m] * 1024 + 512 + k0];
  const float4 bv = *(const float4*)&br1[k0];
  float v0 = fmaxf(u.x + w.x + bv.x, 0.f);
  float v1 = fmaxf(u.y + w.y + bv.y, 0.f);
  float v2 = fmaxf(u.z + w.z + bv.z, 0.f);
  float v3 = fmaxf(u.w + w.w + bv.w, 0.f);
  ushort4 hi, lo;
  hi.x = f2bf(v0); lo.x = f2bf(v0 - bf2f(hi.x));
  hi.y = f2bf(v1); lo.y = f2bf(v1 - bf2f(hi.y));
  hi.z = f2bf(v2); lo.z = f2bf(v2 - bf2f(hi.z));
  hi.w = f2bf(v3); lo.w = f2bf(v3 - bf2f(hi.w));
  *(ushort4*)&H1c[(long)rlocal * 1024 + k0]       = hi;
  *(ushort4*)&H1c[(long)rlocal * 1024 + 512 + k0] = lo;
}

__global__ void scatter_k(const ushort_t* __restrict__ eff, ushort_t* __restrict__ agg) {
  int bn = blockIdx.x;
  int b = bn >> 5, n = bn & 31, f = threadIdx.x;   // 128 threads = E_
  float s = 0.f;
#pragma unroll
  for (int i = 0; i < N_; ++i) {
    if (i == n) continue;
    int jj = (n < i) ? n : (n - 1);
    int e = i * 31 + jj;
    long base = ((long)b * NREL_ + e) * 256;
    s += bf2f(eff[base + f]) + bf2f(eff[base + 128 + f]);
  }
  long obase = ((long)b * N_ + n) * 256;
  ushort_t hi = f2bf(s);
  agg[obase + f]       = hi;
  agg[obase + 128 + f] = f2bf(s - bf2f(hi));
}

__global__ void head_k(const ushort_t* __restrict__ ent, const float* __restrict__ Wl,
                       const float* __restrict__ bl, float* __restrict__ out, int t) {
  int b = blockIdx.x >> 2, n = blockIdx.x & 3, lane = threadIdx.x;   // 64 threads
  const ushort_t* e = ent + (long)(b * N_ + n) * 1024;
  float a0 = 0.f, a1 = 0.f;
  for (int k = lane; k < D_; k += 64) {
    float v = bf2f(e[k]) + bf2f(e[512 + k]);
    a0 += v * Wl[2 * k]; a1 += v * Wl[2 * k + 1];
  }
#pragma unroll
  for (int s = 32; s > 0; s >>= 1) { a0 += __shfl_down(a0, s); a1 += __shfl_down(a1, s); }
  if (lane == 0) {
    out[((long)b * T_ + t) * 8 + n * 2 + 0] = a0 + bl[0];
    out[((long)b * T_ + t) * 8 + n * 2 + 1] = a1 + bl[1];
  }
}

// ---------- launch ----------
extern "C" void kernel_launch(void* const* d_in, const int* in_sizes, int n_in,
                              void* d_out, int out_size, void* d_ws, size_t ws_size,
                              hipStream_t stream) {
  const float* entity = (const float*)d_in[0];
  const float* Wr1 = (const float*)d_in[3];  const float* br1 = (const float*)d_in[4];
  const float* Wr2 = (const float*)d_in[5];  const float* br2 = (const float*)d_in[6];
  const float* Wr3 = (const float*)d_in[7];  const float* br3 = (const float*)d_in[8];
  const float* Wr4 = (const float*)d_in[9];  const float* br4 = (const float*)d_in[10];
  const float* Wo1 = (const float*)d_in[11]; const float* bo1 = (const float*)d_in[12];
  const float* Wo2 = (const float*)d_in[13]; const float* bo2 = (const float*)d_in[14];
  const float* Wl  = (const float*)d_in[15]; const float* bl  = (const float*)d_in[16];

  const size_t fixedBytes = (size_t)70 * 1024 * 1024;
  int nchunk = 4;
  for (int c = 1; c <= 4; c *= 2) {
    size_t tot = fixedBytes + 2 * ((size_t)(MROWS / c) * 1024 * 2);
    if (tot <= ws_size) { nchunk = c; break; }
  }
  const int CH = MROWS / nchunk;

  char* ws = (char*)d_ws;
  size_t off = 0;
  auto alloc = [&](size_t bytes) -> void* {
    void* p = ws + off; off = (off + bytes + 255) & ~(size_t)255; return p;
  };
  ushort_t* entP0 = (ushort_t*)alloc((size_t)MOBJ * 1024 * 2);
  ushort_t* entP1 = (ushort_t*)alloc((size_t)MOBJ * 1024 * 2);
  float* UV = (float*)alloc((size_t)MOBJ * 1024 * 4);
  ushort_t* eff = (ushort_t*)alloc((size_t)MROWS * 256 * 2);
  ushort_t* agg = (ushort_t*)alloc((size_t)MOBJ * 256 * 2);
  ushort_t* G   = (ushort_t*)alloc((size_t)MOBJ * 1024 * 2);
  ushort_t* WUVt = (ushort_t*)alloc((size_t)1024 * 1536 * 2);
  ushort_t* Wr2t = (ushort_t*)alloc((size_t)512 * 1536 * 2);
  ushort_t* Wr3t = (ushort_t*)alloc((size_t)128 * 1536 * 2);
  ushort_t* Wr4t = (ushort_t*)alloc((size_t)128 * 384 * 2);
  ushort_t* Wo1t = (ushort_t*)alloc((size_t)512 * 1920 * 2);
  ushort_t* Wo2t = (ushort_t*)alloc((size_t)512 * 1536 * 2);
  int* srcN = (int*)alloc((size_t)MROWS * 4);
  int* dstN = (int*)alloc((size_t)MROWS * 4);
  ushort_t* H1c = (ushort_t*)alloc((size_t)CH * 1024 * 2);
  ushort_t* H2c = (ushort_t*)alloc((size_t)CH * 1024 * 2);
  (void)in_sizes; (void)n_in; (void)out_size;

  tr_uv_k<<<(1024 * 512 + 255) / 256, 256, 0, stream>>>(Wr1, WUVt);
  transpose_cvt_split_k<<<(512 * 512 + 255) / 256, 256, 0, stream>>>(Wr2, Wr2t, 512, 512);
  transpose_cvt_split_k<<<(512 * 128 + 255) / 256, 256, 0, stream>>>(Wr3, Wr3t, 512, 128);
  transpose_cvt_split_k<<<(128 * 128 + 255) / 256, 256, 0, stream>>>(Wr4, Wr4t, 128, 128);
  transpose_cvt_split_k<<<(640 * 512 + 255) / 256, 256, 0, stream>>>(Wo1, Wo1t, 640, 512);
  transpose_cvt_split_k<<<(512 * 512 + 255) / 256, 256, 0, stream>>>(Wo2, Wo2t, 512, 512);
  tables_k<<<(MROWS + 255) / 256, 256, 0, stream>>>(srcN, dstN);
  cvt_split_k<<<(MOBJ * D_ + 255) / 256, 256, 0, stream>>>(entity, entP0, MOBJ * D_, D_);

  float* outP    = (float*)d_out;
  float* lastEnt = outP + (size_t)B_ * T_ * 8;

  ushort_t* cur = entP0;
  ushort_t* nxt = entP1;
  for (int t = 0; t < T_; ++t) {
    // UV = ent @ [Wr1_top | Wr1_bot]  (f32 out)  [2048 x 1024], TM=64 TN=128 -> 256 blocks
    gemm_k<0, false, false, true, 64, 128><<<dim3(8, MOBJ / 64), 256, 0, stream>>>(
        cur, nullptr, WUVt, nullptr, nullptr, UV, MOBJ, 1024, 512);

    for (int c = 0; c < nchunk; ++c) {
      const long r0 = (long)c * CH;
      assemble_h1_k<<<CH / 2, 256, 0, stream>>>(UV, srcN, dstN, br1, H1c, r0);
      // GEMM2: H1c @ Wr2 -> H2c, relu  (256x256 8-wave kernel)
      gemm2_256_k<<<dim3(2, CH / 256), 512, 0, stream>>>(H1c, Wr2t, br2, H2c, CH);
      // fused GEMM3+GEMM4: H2c -> eff chunk
      gemm34_k<<<dim3(1, CH / 128), 256, 0, stream>>>(
          H2c, Wr3t, br3, Wr4t, br4, eff + r0 * 256);
    }
    scatter_k<<<MOBJ, 128, 0, stream>>>(eff, agg);
    // GEMM5: concat(ent, agg) [2048,640] @ Wo1 -> G, relu  (TM=64 TN=64 -> 256 blocks)
    gemm_k<2, true, true, false, 64, 64><<<dim3(8, MOBJ / 64), 256, 0, stream>>>(
        cur, agg, Wo1t, bo1, G, nullptr, MOBJ, 512, 640);
    // GEMM6: G @ Wo2 -> new entity (+ f32 last_entity on final step)
    float* cf = (t == T_ - 1) ? lastEnt : nullptr;
    gemm_k<0, false, true, true, 64, 64><<<dim3(8, MOBJ / 64), 256, 0, stream>>>(
        G, nullptr, Wo2t, bo2, nxt, cf, MOBJ, 512, 512);
    head_k<<<256, 64, 0, stream>>>(nxt, Wl, bl, outP, t);

    ushort_t* tmp = cur; cur = nxt; nxt = tmp;
  }
}

// Round 9
// 5077.798 us; speedup vs baseline: 1.1768x; 1.0002x over previous
//
#include <hip/hip_runtime.h>
#include <stdint.h>
#include <stddef.h>

// ---------- constants ----------
#define B_    64
#define N_    32
#define NREL_ 992
#define D_    512
#define E_    128
#define H_    512
#define T_    16
#define MROWS (B_ * NREL_)   // 63488
#define MOBJ  (B_ * N_)      // 2048

typedef unsigned short ushort_t;
typedef __attribute__((ext_vector_type(8))) short bf16x8;   // 8 bf16 = 4 VGPRs (MFMA A/B frag)
typedef __attribute__((ext_vector_type(4))) float f32x4;    // MFMA C/D frag

typedef __attribute__((address_space(1))) const void gvoid;
typedef __attribute__((address_space(3))) void lvoid;

__device__ __forceinline__ float bf2f(ushort_t u) {
  union { unsigned int i; float f; } v; v.i = ((unsigned int)u) << 16; return v.f;
}
__device__ __forceinline__ ushort_t f2bf(float f) {   // round-to-nearest-even
  union { float f; unsigned int i; } v; v.f = f;
  unsigned int u = v.i;
  u += 0x7FFFu + ((u >> 16) & 1u);
  return (ushort_t)(u >> 16);
}
__device__ __forceinline__ void gload_lds16(const void* g, void* l) {
  __builtin_amdgcn_global_load_lds((gvoid*)g, (lvoid*)l, 16, 0, 0);
}

// ---------- TMxTN MFMA GEMM, 3xBF16 fp32 emulation (R6 structure) ----------
// BK=64, double-buffered LDS, counted vmcnt, raw s_barrier, setprio around
// MFMA clusters, XOR bank-swizzle (pre-swizzled global source + swizzled read).
// MODE 0: A rows plain split [M][2K] = [hi K | lo K].
// MODE 2: logical row m = concat(ent[m](512), agg[m](128)); K=640.
template<int MODE, bool RELU, bool WBF16, bool WF32, int TM, int TN>
__global__ __launch_bounds__(256) void gemm_k(
    const ushort_t* __restrict__ A, const ushort_t* __restrict__ A2,
    const ushort_t* __restrict__ Bt, const float* __restrict__ bias,
    ushort_t* __restrict__ C, float* __restrict__ Cf,
    int M, int N, int K)
{
  constexpr int MI = TM / 32;
  constexpr int NB = TN / 32;
  constexpr int NJ = TN / 32;
  __shared__ ushort_t As[2][TM * 64];
  __shared__ ushort_t Bs[2][TN * 64];

  const int tid  = threadIdx.x;
  const int lane = tid & 63;
  const int wave = tid >> 6;

  const int nwg  = gridDim.x * gridDim.y;
  const int orig = blockIdx.y * gridDim.x + blockIdx.x;
  const int xcd  = orig & 7;
  const int q    = nwg >> 3, r = nwg & 7;
  const int nid  = (xcd < r ? xcd * (q + 1) : r * (q + 1) + (xcd - r) * q) + (orig >> 3);
  const int m0 = (nid / gridDim.x) * TM;
  const int n0 = (nid % gridDim.x) * TN;

  const int wr = (wave >> 1) * (TM / 2);
  const int wc = (wave & 1) * (TN / 2);

  const int srow = tid >> 3;
  const int scol = (((tid & 7) ^ (srow & 7)) * 8);

  long aoff[MI]; long aoff2[MI];
#pragma unroll
  for (int rr = 0; rr < MI; ++rr) {
    int m = m0 + rr * 32 + srow;
    if (MODE == 0) { aoff[rr] = (long)m * (2 * K) + scol; aoff2[rr] = 0; }
    else           { aoff[rr] = (long)m * 1024 + scol; aoff2[rr] = (long)m * 256 + scol; }
  }
  long boff[NB];
#pragma unroll
  for (int rr = 0; rr < NB; ++rr) boff[rr] = (long)(n0 + rr * 32 + srow) * (3 * K) + scol;

  const int NT = (3 * K) >> 6;

  auto stage = [&](int kt, int b) {
    const int kpp = kt * 64;
    const int seg = (kpp >= 2 * K) ? 2 : ((kpp >= K) ? 1 : 0);
    const int k   = kpp - seg * K;
    const bool lop = (seg == 1);
#pragma unroll
    for (int rr = 0; rr < MI; ++rr) {
      const ushort_t* src;
      if (MODE == 0) {
        src = A + aoff[rr] + (lop ? K : 0) + k;
      } else {
        if (k < 512) src = A  + aoff[rr]  + (lop ? 512 : 0) + k;
        else         src = A2 + aoff2[rr] + (lop ? 128 : 0) + (k - 512);
      }
      gload_lds16(src, &As[b][(rr * 32 + wave * 8) * 64]);
    }
#pragma unroll
    for (int rr = 0; rr < NB; ++rr)
      gload_lds16(Bt + boff[rr] + kpp, &Bs[b][(rr * 32 + wave * 8) * 64]);
  };

  f32x4 zero = {0.f, 0.f, 0.f, 0.f};
  f32x4 acc[MI][NJ];
#pragma unroll
  for (int i = 0; i < MI; ++i)
#pragma unroll
    for (int j = 0; j < NJ; ++j) acc[i][j] = zero;

  stage(0, 0);
  if (NT > 1) stage(1, 1);

  for (int kt = 0; kt < NT; ++kt) {
    const int b = kt & 1;
    if (kt + 1 < NT) {
      if constexpr (MI + NB == 8)      asm volatile("s_waitcnt vmcnt(8)" ::: "memory");
      else if constexpr (MI + NB == 6) asm volatile("s_waitcnt vmcnt(6)" ::: "memory");
      else                             asm volatile("s_waitcnt vmcnt(4)" ::: "memory");
    } else {
      asm volatile("s_waitcnt vmcnt(0)" ::: "memory");
    }
    __builtin_amdgcn_s_barrier();
    asm volatile("" ::: "memory");

#pragma unroll
    for (int kk = 0; kk < 2; ++kk) {
      const int cel = (((kk * 4 + (lane >> 4)) ^ (lane & 7)) << 3);
      bf16x8 af[MI];
#pragma unroll
      for (int i = 0; i < MI; ++i)
        af[i] = *(const bf16x8*)&As[b][(wr + i * 16 + (lane & 15)) * 64 + cel];
#pragma unroll
      for (int jh = 0; jh < NJ / 2; ++jh) {
        bf16x8 bfr[2];
#pragma unroll
        for (int jj = 0; jj < 2; ++jj)
          bfr[jj] = *(const bf16x8*)&Bs[b][(wc + (jh * 2 + jj) * 16 + (lane & 15)) * 64 + cel];
        __builtin_amdgcn_s_setprio(1);
#pragma unroll
        for (int i = 0; i < MI; ++i)
#pragma unroll
          for (int jj = 0; jj < 2; ++jj)
            acc[i][jh * 2 + jj] =
                __builtin_amdgcn_mfma_f32_16x16x32_bf16(af[i], bfr[jj], acc[i][jh * 2 + jj], 0, 0, 0);
        __builtin_amdgcn_s_setprio(0);
      }
    }

    asm volatile("" ::: "memory");
    __builtin_amdgcn_s_barrier();
    asm volatile("" ::: "memory");
    if (kt + 2 < NT) stage(kt + 2, b);
  }

  const long strideC = 2 * (long)N;
#pragma unroll
  for (int j = 0; j < NJ; ++j) {
    const int col = n0 + wc + j * 16 + (lane & 15);
    const float bv = bias ? bias[col] : 0.f;
#pragma unroll
    for (int i = 0; i < MI; ++i) {
      const int rowb = m0 + wr + i * 16 + (lane >> 4) * 4;
#pragma unroll
      for (int rr = 0; rr < 4; ++rr) {
        float v = acc[i][j][rr] + bv;
        if (RELU) v = fmaxf(v, 0.f);
        if (WBF16) {
          const ushort_t hi = f2bf(v);
          const float lof = v - bf2f(hi);
          C[(long)(rowb + rr) * strideC + col]     = hi;
          C[(long)(rowb + rr) * strideC + N + col] = f2bf(lof);
        }
        if (WF32) { if (Cf) Cf[(long)(rowb + rr) * N + col] = v; }
      }
    }
  }
}

// ---------- GEMM2: 256x256 tile, 8 waves, TRUE 8-PHASE interleave ----------
// H2 = relu(H1 @ Wr2 + br2); N=512, K=512, K''=1536 -> 24 K-tiles, 12 iters x
// 2 tiles. LDS per matrix: [tile-parity buf][kk-half][256 rows][32 cols]
// (16KB regions). Each phase: {4-8 ds_read_b128 || stage one half-region
// (2 gload_lds, targeting the region freed one phase ago) || vmcnt at odd
// phases || barrier || 16 MFMA (setprio) || barrier}. Stage->read lag >= 5
// phases; vmcnt(6) (=3 stages) guarantees landing. Tail iter: vmcnt(4)@p3,
// vmcnt(0)@p5. Accumulation order identical to 2-phase version (bit-exact).
__global__ __launch_bounds__(512) void gemm2_8ph_k(
    const ushort_t* __restrict__ A,   // H1 split [M][1024]
    const ushort_t* __restrict__ Bt,  // Wr2t [512][1536]
    const float* __restrict__ bias,
    ushort_t* __restrict__ C,         // H2 split [M][1024]
    int M)
{
  __shared__ ushort_t As[2][2][256 * 32];   // [buf][kk][row*32+col]
  __shared__ ushort_t Bs[2][2][256 * 32];

  const int tid  = threadIdx.x;
  const int lane = tid & 63;
  const int wave = tid >> 6;
  const int l15  = lane & 15;

  const int nwg  = gridDim.x * gridDim.y;
  const int orig = blockIdx.y * gridDim.x + blockIdx.x;
  const int xcd  = orig & 7;
  const int q    = nwg >> 3, r = nwg & 7;
  const int nid  = (xcd < r ? xcd * (q + 1) : r * (q + 1) + (xcd - r) * q) + (orig >> 3);
  const int m0 = (nid / gridDim.x) * 256;
  const int n0 = (nid % gridDim.x) * 256;

  const int wr = (wave >> 2) * 128;   // 0 or 128
  const int wc = (wave & 3) * 64;     // 0,64,128,192

  const int trow = tid >> 2;                                  // 0..127
  const int scol = (((tid & 3) ^ ((trow >> 1) & 3)) * 8);     // swizzled col in half

  long aoffr[2], boffr[2];
#pragma unroll
  for (int rr = 0; rr < 2; ++rr) {
    aoffr[rr] = (long)(m0 + rr * 128 + trow) * 1024 + scol;
    boffr[rr] = (long)(n0 + rr * 128 + trow) * 1536 + scol;
  }

  auto stageA = [&](int kt, int kk) {   // A half (kt&1 buf): 2 gload_lds
    const int kpp = kt * 64;
    const int seg = (kpp >= 1024) ? 2 : ((kpp >= 512) ? 1 : 0);
    const int k   = kpp - seg * 512;
    const int loff = (seg == 1) ? 512 : 0;
    const int b = kt & 1;
#pragma unroll
    for (int rr = 0; rr < 2; ++rr)
      gload_lds16(A + aoffr[rr] + loff + k + kk * 32, &As[b][kk][(rr * 128 + wave * 16) * 32]);
  };
  auto stageB = [&](int kt, int kk) {
    const int kpp = kt * 64;
    const int b = kt & 1;
#pragma unroll
    for (int rr = 0; rr < 2; ++rr)
      gload_lds16(Bt + boffr[rr] + kpp + kk * 32, &Bs[b][kk][(rr * 128 + wave * 16) * 32]);
  };

  f32x4 zero = {0.f, 0.f, 0.f, 0.f};
  f32x4 acc[8][4];
#pragma unroll
  for (int i = 0; i < 8; ++i)
#pragma unroll
    for (int j = 0; j < 4; ++j) acc[i][j] = zero;

  // macros keep acc/af indices compile-time (rule #20)
#define READB(BUF, KK, BF)                                                     \
  _Pragma("unroll")                                                            \
  for (int j = 0; j < 4; ++j) {                                                \
    const int row = wc + j * 16 + l15;                                         \
    const int slot = ((lane >> 4) ^ ((row >> 1) & 3));                         \
    BF[j] = *(const bf16x8*)&Bs[BUF][KK][row * 32 + slot * 8];                 \
  }

#define PHASE(BUF, KK, IH, BF)                                                 \
  {                                                                            \
    bf16x8 af_[4];                                                             \
    _Pragma("unroll")                                                          \
    for (int i = 0; i < 4; ++i) {                                              \
      const int row = wr + (IH) * 64 + i * 16 + l15;                           \
      const int slot = ((lane >> 4) ^ ((row >> 1) & 3));                       \
      af_[i] = *(const bf16x8*)&As[BUF][KK][row * 32 + slot * 8];              \
    }                                                                          \
    __builtin_amdgcn_s_barrier();                                              \
    __builtin_amdgcn_sched_barrier(0);                                         \
    __builtin_amdgcn_s_setprio(1);                                             \
    _Pragma("unroll")                                                          \
    for (int i = 0; i < 4; ++i)                                                \
      _Pragma("unroll")                                                        \
      for (int j = 0; j < 4; ++j)                                              \
        acc[(IH) * 4 + i][j] = __builtin_amdgcn_mfma_f32_16x16x32_bf16(        \
            af_[i], BF[j], acc[(IH) * 4 + i][j], 0, 0, 0);                     \
    __builtin_amdgcn_s_setprio(0);                                             \
    __builtin_amdgcn_sched_barrier(0);                                         \
    __builtin_amdgcn_s_barrier();                                              \
  }

  // prologue: tile0 fully + tile1 kk0 (6 stages), drain, enter loop
  stageA(0, 0); stageB(0, 0); stageA(0, 1); stageB(0, 1); stageA(1, 0); stageB(1, 0);
  asm volatile("s_waitcnt vmcnt(0)" ::: "memory");
  __builtin_amdgcn_s_barrier();

  for (int it = 0; it < 12; ++it) {
    const int kt1 = 2 * it + 1;
    const bool more = (it < 11);     // tiles kt+2/kt+3 exist
    bf16x8 bf[4];

    // p0: compute (buf0,kk0,ih0); stage A-kk1(kt1) -> buf1 (region freed last iter)
    READB(0, 0, bf);
    stageA(kt1, 1);
    PHASE(0, 0, 0, bf);
    // p1: compute (buf0,kk0,ih1); stage B-kk1(kt1)
    stageB(kt1, 1);
    asm volatile("s_waitcnt vmcnt(6)" ::: "memory");
    PHASE(0, 0, 1, bf);
    // p2: compute (buf0,kk1,ih0); stage A-kk0(kt+2) over freed buf0-kk0
    READB(0, 1, bf);
    if (more) stageA(kt1 + 1, 0);
    PHASE(0, 1, 0, bf);
    // p3: compute (buf0,kk1,ih1); stage B-kk0(kt+2)
    if (more) { stageB(kt1 + 1, 0); asm volatile("s_waitcnt vmcnt(6)" ::: "memory"); }
    else      { asm volatile("s_waitcnt vmcnt(4)" ::: "memory"); }
    PHASE(0, 1, 1, bf);
    // p4: compute (buf1,kk0,ih0); stage A-kk1(kt+2) over freed buf0-kk1
    READB(1, 0, bf);
    if (more) stageA(kt1 + 1, 1);
    PHASE(1, 0, 0, bf);
    // p5: compute (buf1,kk0,ih1); stage B-kk1(kt+2)
    if (more) { stageB(kt1 + 1, 1); asm volatile("s_waitcnt vmcnt(6)" ::: "memory"); }
    else      { asm volatile("s_waitcnt vmcnt(0)" ::: "memory"); }
    PHASE(1, 0, 1, bf);
    // p6: compute (buf1,kk1,ih0); stage A-kk0(kt+3) over freed buf1-kk0
    READB(1, 1, bf);
    if (more) stageA(kt1 + 2, 0);
    PHASE(1, 1, 0, bf);
    // p7: compute (buf1,kk1,ih1); stage B-kk0(kt+3)
    if (more) { stageB(kt1 + 2, 0); asm volatile("s_waitcnt vmcnt(6)" ::: "memory"); }
    PHASE(1, 1, 1, bf);
  }
#undef READB
#undef PHASE

  // epilogue: relu(acc + bias) -> H2 split [row][1024] = [hi512 | lo512]
#pragma unroll
  for (int j = 0; j < 4; ++j) {
    const int col = n0 + wc + j * 16 + l15;
    const float bv = bias[col];
#pragma unroll
    for (int i = 0; i < 8; ++i) {
      const int rowb = m0 + wr + i * 16 + (lane >> 4) * 4;
#pragma unroll
      for (int rr = 0; rr < 4; ++rr) {
        float v = fmaxf(acc[i][j][rr] + bv, 0.f);
        const ushort_t hi = f2bf(v);
        C[(long)(rowb + rr) * 1024 + col]       = hi;
        C[(long)(rowb + rr) * 1024 + 512 + col] = f2bf(v - bf2f(hi));
      }
    }
  }
}

// ---------- fused GEMM3+GEMM4: eff = relu(relu(H2@W3+b3)@W4+b4) ----------
__global__ __launch_bounds__(256) void gemm34_k(
    const ushort_t* __restrict__ A, const ushort_t* __restrict__ W3t,
    const float* __restrict__ b3, const ushort_t* __restrict__ W4t,
    const float* __restrict__ b4, ushort_t* __restrict__ eff)
{
  __shared__ ushort_t SM[4][128 * 64];
  ushort_t* SMf = &SM[0][0];

  const int tid  = threadIdx.x;
  const int lane = tid & 63;
  const int wave = tid >> 6;

  const int nwg  = gridDim.y;
  const int orig = blockIdx.y;
  const int xcd  = orig & 7;
  const int q    = nwg >> 3, r = nwg & 7;
  const int nid  = (xcd < r ? xcd * (q + 1) : r * (q + 1) + (xcd - r) * q) + (orig >> 3);
  const int m0   = nid * 128;

  const int wr = (wave >> 1) * 64;
  const int wc = (wave & 1) * 64;
  const int srow = tid >> 3;
  const int scol = (((tid & 7) ^ (srow & 7)) * 8);

  long aoff[4];
#pragma unroll
  for (int rr = 0; rr < 4; ++rr) aoff[rr] = (long)(m0 + rr * 32 + srow) * 1024 + scol;
  long boff[4];
#pragma unroll
  for (int rr = 0; rr < 4; ++rr) boff[rr] = (long)(rr * 32 + srow) * 1536 + scol;

  auto stage = [&](int kt, int b) {
    const int kpp = kt * 64;
    const int seg = (kpp >= 1024) ? 2 : ((kpp >= 512) ? 1 : 0);
    const int k   = kpp - seg * 512;
    const bool lop = (seg == 1);
#pragma unroll
    for (int rr = 0; rr < 4; ++rr)
      gload_lds16(A + aoff[rr] + (lop ? 512 : 0) + k, &SM[b][(rr * 32 + wave * 8) * 64]);
#pragma unroll
    for (int rr = 0; rr < 4; ++rr)
      gload_lds16(W3t + boff[rr] + kpp, &SM[2 + b][(rr * 32 + wave * 8) * 64]);
  };

  f32x4 zero = {0.f, 0.f, 0.f, 0.f};
  f32x4 acc[4][4];
#pragma unroll
  for (int i = 0; i < 4; ++i)
#pragma unroll
    for (int j = 0; j < 4; ++j) acc[i][j] = zero;

  stage(0, 0);
  stage(1, 1);

  for (int kt = 0; kt < 24; ++kt) {
    const int b = kt & 1;
    if (kt + 1 < 24) asm volatile("s_waitcnt vmcnt(8)" ::: "memory");
    else             asm volatile("s_waitcnt vmcnt(0)" ::: "memory");
    __builtin_amdgcn_s_barrier();
    asm volatile("" ::: "memory");

#pragma unroll
    for (int kk = 0; kk < 2; ++kk) {
      const int cel = (((kk * 4 + (lane >> 4)) ^ (lane & 7)) << 3);
      bf16x8 af[4];
#pragma unroll
      for (int i = 0; i < 4; ++i)
        af[i] = *(const bf16x8*)&SM[b][(wr + i * 16 + (lane & 15)) * 64 + cel];
#pragma unroll
      for (int jh = 0; jh < 2; ++jh) {
        bf16x8 bfr[2];
#pragma unroll
        for (int jj = 0; jj < 2; ++jj)
          bfr[jj] = *(const bf16x8*)&SM[2 + b][(wc + (jh * 2 + jj) * 16 + (lane & 15)) * 64 + cel];
        __builtin_amdgcn_s_setprio(1);
#pragma unroll
        for (int i = 0; i < 4; ++i)
#pragma unroll
          for (int jj = 0; jj < 2; ++jj)
            acc[i][jh * 2 + jj] =
                __builtin_amdgcn_mfma_f32_16x16x32_bf16(af[i], bfr[jj], acc[i][jh * 2 + jj], 0, 0, 0);
        __builtin_amdgcn_s_setprio(0);
      }
    }

    asm volatile("" ::: "memory");
    __builtin_amdgcn_s_barrier();
    asm volatile("" ::: "memory");
    if (kt + 2 < 24) stage(kt + 2, b);
  }

  // epilogue 1: relu(acc + b3) -> split H3 tile in LDS (swizzled subtiles)
#pragma unroll
  for (int j = 0; j < 4; ++j) {
    const int col = wc + j * 16 + (lane & 15);
    const float bv = b3[col];
    const int thi = col >> 6, c = col & 63;
#pragma unroll
    for (int i = 0; i < 4; ++i) {
      const int rowb = wr + i * 16 + (lane >> 4) * 4;
#pragma unroll
      for (int rr = 0; rr < 4; ++rr) {
        const int row = rowb + rr;
        float v = fmaxf(acc[i][j][rr] + bv, 0.f);
        const ushort_t hi = f2bf(v);
        const ushort_t lo = f2bf(v - bf2f(hi));
        const int slot = ((c >> 3) ^ (row & 7)) * 8 + (c & 7);
        SMf[(thi * 128 + row) * 64 + slot]       = hi;
        SMf[((2 + thi) * 128 + row) * 64 + slot] = lo;
      }
    }
  }
  asm volatile("s_waitcnt lgkmcnt(0)" ::: "memory");
  __builtin_amdgcn_sched_barrier(0);
  __builtin_amdgcn_s_barrier();
  asm volatile("" ::: "memory");

  // phase 2: eff_tile = relu(H3_tile @ W4 + b4).
  f32x4 acc2[4][4];
#pragma unroll
  for (int i = 0; i < 4; ++i)
#pragma unroll
    for (int j = 0; j < 4; ++j) acc2[i][j] = zero;

#pragma unroll
  for (int kt2 = 0; kt2 < 6; ++kt2) {
    const int phys = kt2 & 3;
#pragma unroll
    for (int kk = 0; kk < 2; ++kk) {
      const int cel = (((kk * 4 + (lane >> 4)) ^ (lane & 7)) << 3);
      bf16x8 af[4];
#pragma unroll
      for (int i = 0; i < 4; ++i)
        af[i] = *(const bf16x8*)&SMf[(phys * 128 + wr + i * 16 + (lane & 15)) * 64 + cel];
#pragma unroll
      for (int jh = 0; jh < 2; ++jh) {
        bf16x8 bfr[2];
#pragma unroll
        for (int jj = 0; jj < 2; ++jj) {
          const int col2 = wc + (jh * 2 + jj) * 16 + (lane & 15);
          bfr[jj] = *(const bf16x8*)&W4t[(long)col2 * 384 + kt2 * 64 + kk * 32 + (lane >> 4) * 8];
        }
        __builtin_amdgcn_s_setprio(1);
#pragma unroll
        for (int i = 0; i < 4; ++i)
#pragma unroll
          for (int jj = 0; jj < 2; ++jj)
            acc2[i][jh * 2 + jj] =
                __builtin_amdgcn_mfma_f32_16x16x32_bf16(af[i], bfr[jj], acc2[i][jh * 2 + jj], 0, 0, 0);
        __builtin_amdgcn_s_setprio(0);
      }
    }
  }

  // epilogue 2: relu(acc2 + b4) -> eff split [row][256]
#pragma unroll
  for (int j = 0; j < 4; ++j) {
    const int col = wc + j * 16 + (lane & 15);
    const float bv = b4[col];
#pragma unroll
    for (int i = 0; i < 4; ++i) {
      const int rowb = m0 + wr + i * 16 + (lane >> 4) * 4;
#pragma unroll
      for (int rr = 0; rr < 4; ++rr) {
        float v = fmaxf(acc2[i][j][rr] + bv, 0.f);
        const ushort_t hi = f2bf(v);
        eff[(long)(rowb + rr) * 256 + col]       = hi;
        eff[(long)(rowb + rr) * 256 + 128 + col] = f2bf(v - bf2f(hi));
      }
    }
  }
}

// ---------- helpers ----------
__global__ void cvt_split_k(const float* __restrict__ x, ushort_t* __restrict__ y,
                            int total, int W) {
  int i = blockIdx.x * 256 + threadIdx.x;
  if (i >= total) return;
  int row = i / W, k = i - row * W;
  float v = x[i];
  ushort_t hi = f2bf(v);
  float lof = v - bf2f(hi);
  y[(long)row * (2 * W) + k]     = hi;
  y[(long)row * (2 * W) + W + k] = f2bf(lof);
}

__global__ void transpose_cvt_split_k(const float* __restrict__ W, ushort_t* __restrict__ Bt,
                                      int K, int N) {
  int idx = blockIdx.x * 256 + threadIdx.x;
  if (idx >= K * N) return;
  int k = idx / N, n = idx - k * N;
  float v = W[idx];
  ushort_t hi = f2bf(v);
  float lof = v - bf2f(hi);
  ushort_t lo = f2bf(lof);
  long base = (long)n * (3 * K);
  Bt[base + k]         = hi;
  Bt[base + K + k]     = hi;
  Bt[base + 2 * K + k] = lo;
}

__global__ void tr_uv_k(const float* __restrict__ W, ushort_t* __restrict__ Bt) {
  int idx = blockIdx.x * 256 + threadIdx.x;
  if (idx >= 1024 * 512) return;
  int n = idx >> 9, k = idx & 511;
  float v = (n < 512) ? W[(long)k * 512 + n] : W[(long)(512 + k) * 512 + (n - 512)];
  ushort_t hi = f2bf(v);
  float lof = v - bf2f(hi);
  long base = (long)n * 1536;
  Bt[base + k]        = hi;
  Bt[base + 512 + k]  = hi;
  Bt[base + 1024 + k] = f2bf(lof);
}

__global__ void tables_k(int* __restrict__ srcN, int* __restrict__ dstN) {
  int m = blockIdx.x * 256 + threadIdx.x;
  if (m >= MROWS) return;
  int b = m / NREL_;
  int e = m - b * NREL_;
  int i = e / 31;
  int jj = e - i * 31;
  int j = jj + (jj >= i ? 1 : 0);
  srcN[m] = b * N_ + i;
  dstN[m] = b * N_ + j;
}

__global__ __launch_bounds__(256) void assemble_h1_k(
    const float* __restrict__ UV, const int* __restrict__ srcN,
    const int* __restrict__ dstN, const float* __restrict__ br1,
    ushort_t* __restrict__ H1c, long r0) {
  const int rlocal = blockIdx.x * 2 + (threadIdx.x >> 7);
  const long m = r0 + rlocal;
  const int k0 = (threadIdx.x & 127) * 4;
  const float4 u  = *(const float4*)&UV[(long)srcN[m] * 1024 + k0];
  const float4 w  = *(const float4*)&UV[(long)dstN[m] * 1024 + 512 + k0];
  const float4 bv = *(const float4*)&br1[k0];
  float v0 = fmaxf(u.x + w.x + bv.x, 0.f);
  float v1 = fmaxf(u.y + w.y + bv.y, 0.f);
  float v2 = fmaxf(u.z + w.z + bv.z, 0.f);
  float v3 = fmaxf(u.w + w.w + bv.w, 0.f);
  ushort4 hi, lo;
  hi.x = f2bf(v0); lo.x = f2bf(v0 - bf2f(hi.x));
  hi.y = f2bf(v1); lo.y = f2bf(v1 - bf2f(hi.y));
  hi.z = f2bf(v2); lo.z = f2bf(v2 - bf2f(hi.z));
  hi.w = f2bf(v3); lo.w = f2bf(v3 - bf2f(hi.w));
  *(ushort4*)&H1c[(long)rlocal * 1024 + k0]       = hi;
  *(ushort4*)&H1c[(long)rlocal * 1024 + 512 + k0] = lo;
}

__global__ void scatter_k(const ushort_t* __restrict__ eff, ushort_t* __restrict__ agg) {
  int bn = blockIdx.x;
  int b = bn >> 5, n = bn & 31, f = threadIdx.x;
  float s = 0.f;
#pragma unroll
  for (int i = 0; i < N_; ++i) {
    if (i == n) continue;
    int jj = (n < i) ? n : (n - 1);
    int e = i * 31 + jj;
    long base = ((long)b * NREL_ + e) * 256;
    s += bf2f(eff[base + f]) + bf2f(eff[base + 128 + f]);
  }
  long obase = ((long)b * N_ + n) * 256;
  ushort_t hi = f2bf(s);
  agg[obase + f]       = hi;
  agg[obase + 128 + f] = f2bf(s - bf2f(hi));
}

__global__ void head_k(const ushort_t* __restrict__ ent, const float* __restrict__ Wl,
                       const float* __restrict__ bl, float* __restrict__ out, int t) {
  int b = blockIdx.x >> 2, n = blockIdx.x & 3, lane = threadIdx.x;
  const ushort_t* e = ent + (long)(b * N_ + n) * 1024;
  float a0 = 0.f, a1 = 0.f;
  for (int k = lane; k < D_; k += 64) {
    float v = bf2f(e[k]) + bf2f(e[512 + k]);
    a0 += v * Wl[2 * k]; a1 += v * Wl[2 * k + 1];
  }
#pragma unroll
  for (int s = 32; s > 0; s >>= 1) { a0 += __shfl_down(a0, s); a1 += __shfl_down(a1, s); }
  if (lane == 0) {
    out[((long)b * T_ + t) * 8 + n * 2 + 0] = a0 + bl[0];
    out[((long)b * T_ + t) * 8 + n * 2 + 1] = a1 + bl[1];
  }
}

// ---------- launch ----------
extern "C" void kernel_launch(void* const* d_in, const int* in_sizes, int n_in,
                              void* d_out, int out_size, void* d_ws, size_t ws_size,
                              hipStream_t stream) {
  const float* entity = (const float*)d_in[0];
  const float* Wr1 = (const float*)d_in[3];  const float* br1 = (const float*)d_in[4];
  const float* Wr2 = (const float*)d_in[5];  const float* br2 = (const float*)d_in[6];
  const float* Wr3 = (const float*)d_in[7];  const float* br3 = (const float*)d_in[8];
  const float* Wr4 = (const float*)d_in[9];  const float* br4 = (const float*)d_in[10];
  const float* Wo1 = (const float*)d_in[11]; const float* bo1 = (const float*)d_in[12];
  const float* Wo2 = (const float*)d_in[13]; const float* bo2 = (const float*)d_in[14];
  const float* Wl  = (const float*)d_in[15]; const float* bl  = (const float*)d_in[16];

  const size_t fixedBytes = (size_t)70 * 1024 * 1024;
  int nchunk = 4;
  for (int c = 1; c <= 4; c *= 2) {
    size_t tot = fixedBytes + 2 * ((size_t)(MROWS / c) * 1024 * 2);
    if (tot <= ws_size) { nchunk = c; break; }
  }
  const int CH = MROWS / nchunk;

  char* ws = (char*)d_ws;
  size_t off = 0;
  auto alloc = [&](size_t bytes) -> void* {
    void* p = ws + off; off = (off + bytes + 255) & ~(size_t)255; return p;
  };
  ushort_t* entP0 = (ushort_t*)alloc((size_t)MOBJ * 1024 * 2);
  ushort_t* entP1 = (ushort_t*)alloc((size_t)MOBJ * 1024 * 2);
  float* UV = (float*)alloc((size_t)MOBJ * 1024 * 4);
  ushort_t* eff = (ushort_t*)alloc((size_t)MROWS * 256 * 2);
  ushort_t* agg = (ushort_t*)alloc((size_t)MOBJ * 256 * 2);
  ushort_t* G   = (ushort_t*)alloc((size_t)MOBJ * 1024 * 2);
  ushort_t* WUVt = (ushort_t*)alloc((size_t)1024 * 1536 * 2);
  ushort_t* Wr2t = (ushort_t*)alloc((size_t)512 * 1536 * 2);
  ushort_t* Wr3t = (ushort_t*)alloc((size_t)128 * 1536 * 2);
  ushort_t* Wr4t = (ushort_t*)alloc((size_t)128 * 384 * 2);
  ushort_t* Wo1t = (ushort_t*)alloc((size_t)512 * 1920 * 2);
  ushort_t* Wo2t = (ushort_t*)alloc((size_t)512 * 1536 * 2);
  int* srcN = (int*)alloc((size_t)MROWS * 4);
  int* dstN = (int*)alloc((size_t)MROWS * 4);
  ushort_t* H1c = (ushort_t*)alloc((size_t)CH * 1024 * 2);
  ushort_t* H2c = (ushort_t*)alloc((size_t)CH * 1024 * 2);
  (void)in_sizes; (void)n_in; (void)out_size;

  tr_uv_k<<<(1024 * 512 + 255) / 256, 256, 0, stream>>>(Wr1, WUVt);
  transpose_cvt_split_k<<<(512 * 512 + 255) / 256, 256, 0, stream>>>(Wr2, Wr2t, 512, 512);
  transpose_cvt_split_k<<<(512 * 128 + 255) / 256, 256, 0, stream>>>(Wr3, Wr3t, 512, 128);
  transpose_cvt_split_k<<<(128 * 128 + 255) / 256, 256, 0, stream>>>(Wr4, Wr4t, 128, 128);
  transpose_cvt_split_k<<<(640 * 512 + 255) / 256, 256, 0, stream>>>(Wo1, Wo1t, 640, 512);
  transpose_cvt_split_k<<<(512 * 512 + 255) / 256, 256, 0, stream>>>(Wo2, Wo2t, 512, 512);
  tables_k<<<(MROWS + 255) / 256, 256, 0, stream>>>(srcN, dstN);
  cvt_split_k<<<(MOBJ * D_ + 255) / 256, 256, 0, stream>>>(entity, entP0, MOBJ * D_, D_);

  float* outP    = (float*)d_out;
  float* lastEnt = outP + (size_t)B_ * T_ * 8;

  ushort_t* cur = entP0;
  ushort_t* nxt = entP1;
  for (int t = 0; t < T_; ++t) {
    gemm_k<0, false, false, true, 64, 128><<<dim3(8, MOBJ / 64), 256, 0, stream>>>(
        cur, nullptr, WUVt, nullptr, nullptr, UV, MOBJ, 1024, 512);

    for (int c = 0; c < nchunk; ++c) {
      const long r0 = (long)c * CH;
      assemble_h1_k<<<CH / 2, 256, 0, stream>>>(UV, srcN, dstN, br1, H1c, r0);
      // GEMM2: H1c @ Wr2 -> H2c, relu  (256x256 8-wave, 8-phase)
      gemm2_8ph_k<<<dim3(2, CH / 256), 512, 0, stream>>>(H1c, Wr2t, br2, H2c, CH);
      gemm34_k<<<dim3(1, CH / 128), 256, 0, stream>>>(
          H2c, Wr3t, br3, Wr4t, br4, eff + r0 * 256);
    }
    scatter_k<<<MOBJ, 128, 0, stream>>>(eff, agg);
    gemm_k<2, true, true, false, 64, 64><<<dim3(8, MOBJ / 64), 256, 0, stream>>>(
        cur, agg, Wo1t, bo1, G, nullptr, MOBJ, 512, 640);
    float* cf = (t == T_ - 1) ? lastEnt : nullptr;
    gemm_k<0, false, true, true, 64, 64><<<dim3(8, MOBJ / 64), 256, 0, stream>>>(
        G, nullptr, Wo2t, bo2, nxt, cf, MOBJ, 512, 512);
    head_k<<<256, 64, 0, stream>>>(nxt, Wl, bl, outP, t);

    ushort_t* tmp = cur; cur = nxt; nxt = tmp;
  }
}

// Round 10
// 4970.026 us; speedup vs baseline: 1.2023x; 1.0217x over previous
//
#include <hip/hip_runtime.h>
#include <stdint.h>
#include <stddef.h>

// ---------- constants ----------
#define B_    64
#define N_    32
#define NREL_ 992
#define D_    512
#define E_    128
#define H_    512
#define T_    16
#define MROWS (B_ * NREL_)   // 63488
#define MOBJ  (B_ * N_)      // 2048

typedef unsigned short ushort_t;
typedef __attribute__((ext_vector_type(8))) short bf16x8;   // 8 bf16 = 4 VGPRs (MFMA A/B frag)
typedef __attribute__((ext_vector_type(4))) float f32x4;    // MFMA C/D frag

typedef __attribute__((address_space(1))) const void gvoid;
typedef __attribute__((address_space(3))) void lvoid;

__device__ __forceinline__ float bf2f(ushort_t u) {
  union { unsigned int i; float f; } v; v.i = ((unsigned int)u) << 16; return v.f;
}
__device__ __forceinline__ ushort_t f2bf(float f) {   // round-to-nearest-even
  union { float f; unsigned int i; } v; v.f = f;
  unsigned int u = v.i;
  u += 0x7FFFu + ((u >> 16) & 1u);
  return (ushort_t)(u >> 16);
}
__device__ __forceinline__ void gload_lds16(const void* g, void* l) {
  __builtin_amdgcn_global_load_lds((gvoid*)g, (lvoid*)l, 16, 0, 0);
}

// ---------- TMxTN MFMA GEMM, 3xBF16 fp32 emulation ----------
// BK=64, double-buffered LDS, counted vmcnt (= exact per-stage load count LPT,
// a no-op-wait here is a race), raw s_barrier, setprio around MFMA clusters,
// XOR bank-swizzle (pre-swizzled global source + swizzled read).
// MODE 0: A rows plain split [M][2K] = [hi K | lo K].
// MODE 2: logical row m = concat(ent[m](512), agg[m](128)); K=640.
// TM in {32,64,128}; TN in {64,128}. TM=32 variants give 512+ blocks for the
// latency-bound M=2048 GEMMs (occupancy >= 4 waves/SIMD).
template<int MODE, bool RELU, bool WBF16, bool WF32, int TM, int TN>
__global__ __launch_bounds__(256) void gemm_k(
    const ushort_t* __restrict__ A, const ushort_t* __restrict__ A2,
    const ushort_t* __restrict__ Bt, const float* __restrict__ bias,
    ushort_t* __restrict__ C, float* __restrict__ Cf,
    int M, int N, int K)
{
  constexpr int MI = (TM + 31) / 32;   // A staging rounds (32 rows each)
  constexpr int AI = TM / 32;          // A frag rows factor
  constexpr int NB = TN / 32;          // B staging rounds
  constexpr int NJ = TN / 32;          // B frags per wave
  constexpr int AF = (TM >= 64) ? TM / 32 : 1;  // A frags per wave (TM/2 / 16)
  __shared__ ushort_t As[2][TM * 64];
  __shared__ ushort_t Bs[2][TN * 64];

  const int tid  = threadIdx.x;
  const int lane = tid & 63;
  const int wave = tid >> 6;

  const int nwg  = gridDim.x * gridDim.y;
  const int orig = blockIdx.y * gridDim.x + blockIdx.x;
  const int xcd  = orig & 7;
  const int q    = nwg >> 3, r = nwg & 7;
  const int nid  = (xcd < r ? xcd * (q + 1) : r * (q + 1) + (xcd - r) * q) + (orig >> 3);
  const int m0 = (nid / gridDim.x) * TM;
  const int n0 = (nid % gridDim.x) * TN;

  const int wr = (wave >> 1) * (TM / 2);
  const int wc = (wave & 1) * (TN / 2);

  const int srow = tid >> 3;          // 0..31: staging row within a 32-row round
  const int scol = (((tid & 7) ^ (srow & 7)) * 8);

  long aoff[MI]; long aoff2[MI];
#pragma unroll
  for (int rr = 0; rr < MI; ++rr) {
    int m = m0 + rr * 32 + srow;
    if (MODE == 0) { aoff[rr] = (long)m * (2 * K) + scol; aoff2[rr] = 0; }
    else           { aoff[rr] = (long)m * 1024 + scol; aoff2[rr] = (long)m * 256 + scol; }
  }
  long boff[NB];
#pragma unroll
  for (int rr = 0; rr < NB; ++rr) boff[rr] = (long)(n0 + rr * 32 + srow) * (3 * K) + scol;

  const int NT = (3 * K) >> 6;

  auto stage = [&](int kt, int b) {
    const int kpp = kt * 64;
    const int seg = (kpp >= 2 * K) ? 2 : ((kpp >= K) ? 1 : 0);
    const int k   = kpp - seg * K;
    const bool lop = (seg == 1);
#pragma unroll
    for (int rr = 0; rr < MI; ++rr) {
      const ushort_t* src;
      if (MODE == 0) {
        src = A + aoff[rr] + (lop ? K : 0) + k;
      } else {
        if (k < 512) src = A  + aoff[rr]  + (lop ? 512 : 0) + k;
        else         src = A2 + aoff2[rr] + (lop ? 128 : 0) + (k - 512);
      }
      gload_lds16(src, &As[b][(rr * 32 + wave * 8) * 64]);
    }
#pragma unroll
    for (int rr = 0; rr < NB; ++rr)
      gload_lds16(Bt + boff[rr] + kpp, &Bs[b][(rr * 32 + wave * 8) * 64]);
  };

  f32x4 zero = {0.f, 0.f, 0.f, 0.f};
  f32x4 acc[AF][NJ];
#pragma unroll
  for (int i = 0; i < AF; ++i)
#pragma unroll
    for (int j = 0; j < NJ; ++j) acc[i][j] = zero;

  stage(0, 0);
  if (NT > 1) stage(1, 1);

  for (int kt = 0; kt < NT; ++kt) {
    const int b = kt & 1;
    if (kt + 1 < NT) {
      // vmcnt == LPT (loads per stage) exactly; wrong constant = race or stall
      if constexpr (MI + NB == 8)      asm volatile("s_waitcnt vmcnt(8)" ::: "memory");
      else if constexpr (MI + NB == 6) asm volatile("s_waitcnt vmcnt(6)" ::: "memory");
      else if constexpr (MI + NB == 5) asm volatile("s_waitcnt vmcnt(5)" ::: "memory");
      else if constexpr (MI + NB == 4) asm volatile("s_waitcnt vmcnt(4)" ::: "memory");
      else                             asm volatile("s_waitcnt vmcnt(3)" ::: "memory");
    } else {
      asm volatile("s_waitcnt vmcnt(0)" ::: "memory");
    }
    __builtin_amdgcn_s_barrier();
    asm volatile("" ::: "memory");

#pragma unroll
    for (int kk = 0; kk < 2; ++kk) {
      const int cel = (((kk * 4 + (lane >> 4)) ^ (lane & 7)) << 3);
      bf16x8 af[AF];
#pragma unroll
      for (int i = 0; i < AF; ++i)
        af[i] = *(const bf16x8*)&As[b][(wr + i * 16 + (lane & 15)) * 64 + cel];
#pragma unroll
      for (int jh = 0; jh < (NJ + 1) / 2; ++jh) {
        bf16x8 bfr[2];
#pragma unroll
        for (int jj = 0; jj < 2 && jh * 2 + jj < NJ; ++jj)
          bfr[jj] = *(const bf16x8*)&Bs[b][(wc + (jh * 2 + jj) * 16 + (lane & 15)) * 64 + cel];
        __builtin_amdgcn_s_setprio(1);
#pragma unroll
        for (int i = 0; i < AF; ++i)
#pragma unroll
          for (int jj = 0; jj < 2 && jh * 2 + jj < NJ; ++jj)
            acc[i][jh * 2 + jj] =
                __builtin_amdgcn_mfma_f32_16x16x32_bf16(af[i], bfr[jj], acc[i][jh * 2 + jj], 0, 0, 0);
        __builtin_amdgcn_s_setprio(0);
      }
    }

    asm volatile("" ::: "memory");
    __builtin_amdgcn_s_barrier();
    asm volatile("" ::: "memory");
    if (kt + 2 < NT) stage(kt + 2, b);
  }

  const long strideC = 2 * (long)N;
#pragma unroll
  for (int j = 0; j < NJ; ++j) {
    const int col = n0 + wc + j * 16 + (lane & 15);
    const float bv = bias ? bias[col] : 0.f;
#pragma unroll
    for (int i = 0; i < AF; ++i) {
      const int rowb = m0 + wr + i * 16 + (lane >> 4) * 4;
#pragma unroll
      for (int rr = 0; rr < 4; ++rr) {
        float v = acc[i][j][rr] + bv;
        if (RELU) v = fmaxf(v, 0.f);
        if (WBF16) {
          const ushort_t hi = f2bf(v);
          const float lof = v - bf2f(hi);
          C[(long)(rowb + rr) * strideC + col]     = hi;
          C[(long)(rowb + rr) * strideC + N + col] = f2bf(lof);
        }
        if (WF32) { if (Cf) Cf[(long)(rowb + rr) * N + col] = v; }
      }
    }
  }
}

// ---------- GEMM2: 256x256 tile, 8 waves, 8-phase interleave (R9, verified) ----------
__global__ __launch_bounds__(512) void gemm2_8ph_k(
    const ushort_t* __restrict__ A,   // H1 split [M][1024]
    const ushort_t* __restrict__ Bt,  // Wr2t [512][1536]
    const float* __restrict__ bias,
    ushort_t* __restrict__ C,         // H2 split [M][1024]
    int M)
{
  __shared__ ushort_t As[2][2][256 * 32];   // [buf][kk][row*32+col]
  __shared__ ushort_t Bs[2][2][256 * 32];

  const int tid  = threadIdx.x;
  const int lane = tid & 63;
  const int wave = tid >> 6;
  const int l15  = lane & 15;

  const int nwg  = gridDim.x * gridDim.y;
  const int orig = blockIdx.y * gridDim.x + blockIdx.x;
  const int xcd  = orig & 7;
  const int q    = nwg >> 3, r = nwg & 7;
  const int nid  = (xcd < r ? xcd * (q + 1) : r * (q + 1) + (xcd - r) * q) + (orig >> 3);
  const int m0 = (nid / gridDim.x) * 256;
  const int n0 = (nid % gridDim.x) * 256;

  const int wr = (wave >> 2) * 128;
  const int wc = (wave & 3) * 64;

  const int trow = tid >> 2;
  const int scol = (((tid & 3) ^ ((trow >> 1) & 3)) * 8);

  long aoffr[2], boffr[2];
#pragma unroll
  for (int rr = 0; rr < 2; ++rr) {
    aoffr[rr] = (long)(m0 + rr * 128 + trow) * 1024 + scol;
    boffr[rr] = (long)(n0 + rr * 128 + trow) * 1536 + scol;
  }

  auto stageA = [&](int kt, int kk) {
    const int kpp = kt * 64;
    const int seg = (kpp >= 1024) ? 2 : ((kpp >= 512) ? 1 : 0);
    const int k   = kpp - seg * 512;
    const int loff = (seg == 1) ? 512 : 0;
    const int b = kt & 1;
#pragma unroll
    for (int rr = 0; rr < 2; ++rr)
      gload_lds16(A + aoffr[rr] + loff + k + kk * 32, &As[b][kk][(rr * 128 + wave * 16) * 32]);
  };
  auto stageB = [&](int kt, int kk) {
    const int kpp = kt * 64;
    const int b = kt & 1;
#pragma unroll
    for (int rr = 0; rr < 2; ++rr)
      gload_lds16(Bt + boffr[rr] + kpp + kk * 32, &Bs[b][kk][(rr * 128 + wave * 16) * 32]);
  };

  f32x4 zero = {0.f, 0.f, 0.f, 0.f};
  f32x4 acc[8][4];
#pragma unroll
  for (int i = 0; i < 8; ++i)
#pragma unroll
    for (int j = 0; j < 4; ++j) acc[i][j] = zero;

#define READB(BUF, KK, BF)                                                     \
  _Pragma("unroll")                                                            \
  for (int j = 0; j < 4; ++j) {                                                \
    const int row = wc + j * 16 + l15;                                         \
    const int slot = ((lane >> 4) ^ ((row >> 1) & 3));                         \
    BF[j] = *(const bf16x8*)&Bs[BUF][KK][row * 32 + slot * 8];                 \
  }

#define PHASE(BUF, KK, IH, BF)                                                 \
  {                                                                            \
    bf16x8 af_[4];                                                             \
    _Pragma("unroll")                                                          \
    for (int i = 0; i < 4; ++i) {                                              \
      const int row = wr + (IH) * 64 + i * 16 + l15;                           \
      const int slot = ((lane >> 4) ^ ((row >> 1) & 3));                       \
      af_[i] = *(const bf16x8*)&As[BUF][KK][row * 32 + slot * 8];              \
    }                                                                          \
    __builtin_amdgcn_s_barrier();                                              \
    __builtin_amdgcn_sched_barrier(0);                                         \
    __builtin_amdgcn_s_setprio(1);                                             \
    _Pragma("unroll")                                                          \
    for (int i = 0; i < 4; ++i)                                                \
      _Pragma("unroll")                                                        \
      for (int j = 0; j < 4; ++j)                                              \
        acc[(IH) * 4 + i][j] = __builtin_amdgcn_mfma_f32_16x16x32_bf16(        \
            af_[i], BF[j], acc[(IH) * 4 + i][j], 0, 0, 0);                     \
    __builtin_amdgcn_s_setprio(0);                                             \
    __builtin_amdgcn_sched_barrier(0);                                         \
    __builtin_amdgcn_s_barrier();                                              \
  }

  stageA(0, 0); stageB(0, 0); stageA(0, 1); stageB(0, 1); stageA(1, 0); stageB(1, 0);
  asm volatile("s_waitcnt vmcnt(0)" ::: "memory");
  __builtin_amdgcn_s_barrier();

  for (int it = 0; it < 12; ++it) {
    const int kt1 = 2 * it + 1;
    const bool more = (it < 11);
    bf16x8 bf[4];

    READB(0, 0, bf);
    stageA(kt1, 1);
    PHASE(0, 0, 0, bf);
    stageB(kt1, 1);
    asm volatile("s_waitcnt vmcnt(6)" ::: "memory");
    PHASE(0, 0, 1, bf);
    READB(0, 1, bf);
    if (more) stageA(kt1 + 1, 0);
    PHASE(0, 1, 0, bf);
    if (more) { stageB(kt1 + 1, 0); asm volatile("s_waitcnt vmcnt(6)" ::: "memory"); }
    else      { asm volatile("s_waitcnt vmcnt(4)" ::: "memory"); }
    PHASE(0, 1, 1, bf);
    READB(1, 0, bf);
    if (more) stageA(kt1 + 1, 1);
    PHASE(1, 0, 0, bf);
    if (more) { stageB(kt1 + 1, 1); asm volatile("s_waitcnt vmcnt(6)" ::: "memory"); }
    else      { asm volatile("s_waitcnt vmcnt(0)" ::: "memory"); }
    PHASE(1, 0, 1, bf);
    READB(1, 1, bf);
    if (more) stageA(kt1 + 2, 0);
    PHASE(1, 1, 0, bf);
    if (more) { stageB(kt1 + 2, 0); asm volatile("s_waitcnt vmcnt(6)" ::: "memory"); }
    PHASE(1, 1, 1, bf);
  }
#undef READB
#undef PHASE

#pragma unroll
  for (int j = 0; j < 4; ++j) {
    const int col = n0 + wc + j * 16 + l15;
    const float bv = bias[col];
#pragma unroll
    for (int i = 0; i < 8; ++i) {
      const int rowb = m0 + wr + i * 16 + (lane >> 4) * 4;
#pragma unroll
      for (int rr = 0; rr < 4; ++rr) {
        float v = fmaxf(acc[i][j][rr] + bv, 0.f);
        const ushort_t hi = f2bf(v);
        C[(long)(rowb + rr) * 1024 + col]       = hi;
        C[(long)(rowb + rr) * 1024 + 512 + col] = f2bf(v - bf2f(hi));
      }
    }
  }
}

// ---------- fused GEMM3+GEMM4: eff = relu(relu(H2@W3+b3)@W4+b4) ----------
__global__ __launch_bounds__(256) void gemm34_k(
    const ushort_t* __restrict__ A, const ushort_t* __restrict__ W3t,
    const float* __restrict__ b3, const ushort_t* __restrict__ W4t,
    const float* __restrict__ b4, ushort_t* __restrict__ eff)
{
  __shared__ ushort_t SM[4][128 * 64];
  ushort_t* SMf = &SM[0][0];

  const int tid  = threadIdx.x;
  const int lane = tid & 63;
  const int wave = tid >> 6;

  const int nwg  = gridDim.y;
  const int orig = blockIdx.y;
  const int xcd  = orig & 7;
  const int q    = nwg >> 3, r = nwg & 7;
  const int nid  = (xcd < r ? xcd * (q + 1) : r * (q + 1) + (xcd - r) * q) + (orig >> 3);
  const int m0   = nid * 128;

  const int wr = (wave >> 1) * 64;
  const int wc = (wave & 1) * 64;
  const int srow = tid >> 3;
  const int scol = (((tid & 7) ^ (srow & 7)) * 8);

  long aoff[4];
#pragma unroll
  for (int rr = 0; rr < 4; ++rr) aoff[rr] = (long)(m0 + rr * 32 + srow) * 1024 + scol;
  long boff[4];
#pragma unroll
  for (int rr = 0; rr < 4; ++rr) boff[rr] = (long)(rr * 32 + srow) * 1536 + scol;

  auto stage = [&](int kt, int b) {
    const int kpp = kt * 64;
    const int seg = (kpp >= 1024) ? 2 : ((kpp >= 512) ? 1 : 0);
    const int k   = kpp - seg * 512;
    const bool lop = (seg == 1);
#pragma unroll
    for (int rr = 0; rr < 4; ++rr)
      gload_lds16(A + aoff[rr] + (lop ? 512 : 0) + k, &SM[b][(rr * 32 + wave * 8) * 64]);
#pragma unroll
    for (int rr = 0; rr < 4; ++rr)
      gload_lds16(W3t + boff[rr] + kpp, &SM[2 + b][(rr * 32 + wave * 8) * 64]);
  };

  f32x4 zero = {0.f, 0.f, 0.f, 0.f};
  f32x4 acc[4][4];
#pragma unroll
  for (int i = 0; i < 4; ++i)
#pragma unroll
    for (int j = 0; j < 4; ++j) acc[i][j] = zero;

  stage(0, 0);
  stage(1, 1);

  for (int kt = 0; kt < 24; ++kt) {
    const int b = kt & 1;
    if (kt + 1 < 24) asm volatile("s_waitcnt vmcnt(8)" ::: "memory");
    else             asm volatile("s_waitcnt vmcnt(0)" ::: "memory");
    __builtin_amdgcn_s_barrier();
    asm volatile("" ::: "memory");

#pragma unroll
    for (int kk = 0; kk < 2; ++kk) {
      const int cel = (((kk * 4 + (lane >> 4)) ^ (lane & 7)) << 3);
      bf16x8 af[4];
#pragma unroll
      for (int i = 0; i < 4; ++i)
        af[i] = *(const bf16x8*)&SM[b][(wr + i * 16 + (lane & 15)) * 64 + cel];
#pragma unroll
      for (int jh = 0; jh < 2; ++jh) {
        bf16x8 bfr[2];
#pragma unroll
        for (int jj = 0; jj < 2; ++jj)
          bfr[jj] = *(const bf16x8*)&SM[2 + b][(wc + (jh * 2 + jj) * 16 + (lane & 15)) * 64 + cel];
        __builtin_amdgcn_s_setprio(1);
#pragma unroll
        for (int i = 0; i < 4; ++i)
#pragma unroll
          for (int jj = 0; jj < 2; ++jj)
            acc[i][jh * 2 + jj] =
                __builtin_amdgcn_mfma_f32_16x16x32_bf16(af[i], bfr[jj], acc[i][jh * 2 + jj], 0, 0, 0);
        __builtin_amdgcn_s_setprio(0);
      }
    }

    asm volatile("" ::: "memory");
    __builtin_amdgcn_s_barrier();
    asm volatile("" ::: "memory");
    if (kt + 2 < 24) stage(kt + 2, b);
  }

#pragma unroll
  for (int j = 0; j < 4; ++j) {
    const int col = wc + j * 16 + (lane & 15);
    const float bv = b3[col];
    const int thi = col >> 6, c = col & 63;
#pragma unroll
    for (int i = 0; i < 4; ++i) {
      const int rowb = wr + i * 16 + (lane >> 4) * 4;
#pragma unroll
      for (int rr = 0; rr < 4; ++rr) {
        const int row = rowb + rr;
        float v = fmaxf(acc[i][j][rr] + bv, 0.f);
        const ushort_t hi = f2bf(v);
        const ushort_t lo = f2bf(v - bf2f(hi));
        const int slot = ((c >> 3) ^ (row & 7)) * 8 + (c & 7);
        SMf[(thi * 128 + row) * 64 + slot]       = hi;
        SMf[((2 + thi) * 128 + row) * 64 + slot] = lo;
      }
    }
  }
  asm volatile("s_waitcnt lgkmcnt(0)" ::: "memory");
  __builtin_amdgcn_sched_barrier(0);
  __builtin_amdgcn_s_barrier();
  asm volatile("" ::: "memory");

  f32x4 acc2[4][4];
#pragma unroll
  for (int i = 0; i < 4; ++i)
#pragma unroll
    for (int j = 0; j < 4; ++j) acc2[i][j] = zero;

#pragma unroll
  for (int kt2 = 0; kt2 < 6; ++kt2) {
    const int phys = kt2 & 3;
#pragma unroll
    for (int kk = 0; kk < 2; ++kk) {
      const int cel = (((kk * 4 + (lane >> 4)) ^ (lane & 7)) << 3);
      bf16x8 af[4];
#pragma unroll
      for (int i = 0; i < 4; ++i)
        af[i] = *(const bf16x8*)&SMf[(phys * 128 + wr + i * 16 + (lane & 15)) * 64 + cel];
#pragma unroll
      for (int jh = 0; jh < 2; ++jh) {
        bf16x8 bfr[2];
#pragma unroll
        for (int jj = 0; jj < 2; ++jj) {
          const int col2 = wc + (jh * 2 + jj) * 16 + (lane & 15);
          bfr[jj] = *(const bf16x8*)&W4t[(long)col2 * 384 + kt2 * 64 + kk * 32 + (lane >> 4) * 8];
        }
        __builtin_amdgcn_s_setprio(1);
#pragma unroll
        for (int i = 0; i < 4; ++i)
#pragma unroll
          for (int jj = 0; jj < 2; ++jj)
            acc2[i][jh * 2 + jj] =
                __builtin_amdgcn_mfma_f32_16x16x32_bf16(af[i], bfr[jj], acc2[i][jh * 2 + jj], 0, 0, 0);
        __builtin_amdgcn_s_setprio(0);
      }
    }
  }

#pragma unroll
  for (int j = 0; j < 4; ++j) {
    const int col = wc + j * 16 + (lane & 15);
    const float bv = b4[col];
#pragma unroll
    for (int i = 0; i < 4; ++i) {
      const int rowb = m0 + wr + i * 16 + (lane >> 4) * 4;
#pragma unroll
      for (int rr = 0; rr < 4; ++rr) {
        float v = fmaxf(acc2[i][j][rr] + bv, 0.f);
        const ushort_t hi = f2bf(v);
        eff[(long)(rowb + rr) * 256 + col]       = hi;
        eff[(long)(rowb + rr) * 256 + 128 + col] = f2bf(v - bf2f(hi));
      }
    }
  }
}

// ---------- helpers ----------
__global__ void cvt_split_k(const float* __restrict__ x, ushort_t* __restrict__ y,
                            int total, int W) {
  int i = blockIdx.x * 256 + threadIdx.x;
  if (i >= total) return;
  int row = i / W, k = i - row * W;
  float v = x[i];
  ushort_t hi = f2bf(v);
  float lof = v - bf2f(hi);
  y[(long)row * (2 * W) + k]     = hi;
  y[(long)row * (2 * W) + W + k] = f2bf(lof);
}

__global__ void transpose_cvt_split_k(const float* __restrict__ W, ushort_t* __restrict__ Bt,
                                      int K, int N) {
  int idx = blockIdx.x * 256 + threadIdx.x;
  if (idx >= K * N) return;
  int k = idx / N, n = idx - k * N;
  float v = W[idx];
  ushort_t hi = f2bf(v);
  float lof = v - bf2f(hi);
  ushort_t lo = f2bf(lof);
  long base = (long)n * (3 * K);
  Bt[base + k]         = hi;
  Bt[base + K + k]     = hi;
  Bt[base + 2 * K + k] = lo;
}

__global__ void tr_uv_k(const float* __restrict__ W, ushort_t* __restrict__ Bt) {
  int idx = blockIdx.x * 256 + threadIdx.x;
  if (idx >= 1024 * 512) return;
  int n = idx >> 9, k = idx & 511;
  float v = (n < 512) ? W[(long)k * 512 + n] : W[(long)(512 + k) * 512 + (n - 512)];
  ushort_t hi = f2bf(v);
  float lof = v - bf2f(hi);
  long base = (long)n * 1536;
  Bt[base + k]        = hi;
  Bt[base + 512 + k]  = hi;
  Bt[base + 1024 + k] = f2bf(lof);
}

__global__ void tables_k(int* __restrict__ srcN, int* __restrict__ dstN) {
  int m = blockIdx.x * 256 + threadIdx.x;
  if (m >= MROWS) return;
  int b = m / NREL_;
  int e = m - b * NREL_;
  int i = e / 31;
  int jj = e - i * 31;
  int j = jj + (jj >= i ? 1 : 0);
  srcN[m] = b * N_ + i;
  dstN[m] = b * N_ + j;
}

__global__ __launch_bounds__(256) void assemble_h1_k(
    const float* __restrict__ UV, const int* __restrict__ srcN,
    const int* __restrict__ dstN, const float* __restrict__ br1,
    ushort_t* __restrict__ H1c, long r0) {
  const int rlocal = blockIdx.x * 2 + (threadIdx.x >> 7);
  const long m = r0 + rlocal;
  const int k0 = (threadIdx.x & 127) * 4;
  const float4 u  = *(const float4*)&UV[(long)srcN[m] * 1024 + k0];
  const float4 w  = *(const float4*)&UV[(long)dstN[m] * 1024 + 512 + k0];
  const float4 bv = *(const float4*)&br1[k0];
  float v0 = fmaxf(u.x + w.x + bv.x, 0.f);
  float v1 = fmaxf(u.y + w.y + bv.y, 0.f);
  float v2 = fmaxf(u.z + w.z + bv.z, 0.f);
  float v3 = fmaxf(u.w + w.w + bv.w, 0.f);
  ushort4 hi, lo;
  hi.x = f2bf(v0); lo.x = f2bf(v0 - bf2f(hi.x));
  hi.y = f2bf(v1); lo.y = f2bf(v1 - bf2f(hi.y));
  hi.z = f2bf(v2); lo.z = f2bf(v2 - bf2f(hi.z));
  hi.w = f2bf(v3); lo.w = f2bf(v3 - bf2f(hi.w));
  *(ushort4*)&H1c[(long)rlocal * 1024 + k0]       = hi;
  *(ushort4*)&H1c[(long)rlocal * 1024 + 512 + k0] = lo;
}

__global__ void scatter_k(const ushort_t* __restrict__ eff, ushort_t* __restrict__ agg) {
  int bn = blockIdx.x;
  int b = bn >> 5, n = bn & 31, f = threadIdx.x;
  float s = 0.f;
#pragma unroll
  for (int i = 0; i < N_; ++i) {
    if (i == n) continue;
    int jj = (n < i) ? n : (n - 1);
    int e = i * 31 + jj;
    long base = ((long)b * NREL_ + e) * 256;
    s += bf2f(eff[base + f]) + bf2f(eff[base + 128 + f]);
  }
  long obase = ((long)b * N_ + n) * 256;
  ushort_t hi = f2bf(s);
  agg[obase + f]       = hi;
  agg[obase + 128 + f] = f2bf(s - bf2f(hi));
}

__global__ void head_k(const ushort_t* __restrict__ ent, const float* __restrict__ Wl,
                       const float* __restrict__ bl, float* __restrict__ out, int t) {
  int b = blockIdx.x >> 2, n = blockIdx.x & 3, lane = threadIdx.x;
  const ushort_t* e = ent + (long)(b * N_ + n) * 1024;
  float a0 = 0.f, a1 = 0.f;
  for (int k = lane; k < D_; k += 64) {
    float v = bf2f(e[k]) + bf2f(e[512 + k]);
    a0 += v * Wl[2 * k]; a1 += v * Wl[2 * k + 1];
  }
#pragma unroll
  for (int s = 32; s > 0; s >>= 1) { a0 += __shfl_down(a0, s); a1 += __shfl_down(a1, s); }
  if (lane == 0) {
    out[((long)b * T_ + t) * 8 + n * 2 + 0] = a0 + bl[0];
    out[((long)b * T_ + t) * 8 + n * 2 + 1] = a1 + bl[1];
  }
}

// ---------- launch ----------
extern "C" void kernel_launch(void* const* d_in, const int* in_sizes, int n_in,
                              void* d_out, int out_size, void* d_ws, size_t ws_size,
                              hipStream_t stream) {
  const float* entity = (const float*)d_in[0];
  const float* Wr1 = (const float*)d_in[3];  const float* br1 = (const float*)d_in[4];
  const float* Wr2 = (const float*)d_in[5];  const float* br2 = (const float*)d_in[6];
  const float* Wr3 = (const float*)d_in[7];  const float* br3 = (const float*)d_in[8];
  const float* Wr4 = (const float*)d_in[9];  const float* br4 = (const float*)d_in[10];
  const float* Wo1 = (const float*)d_in[11]; const float* bo1 = (const float*)d_in[12];
  const float* Wo2 = (const float*)d_in[13]; const float* bo2 = (const float*)d_in[14];
  const float* Wl  = (const float*)d_in[15]; const float* bl  = (const float*)d_in[16];

  const size_t fixedBytes = (size_t)70 * 1024 * 1024;
  int nchunk = 4;
  for (int c = 1; c <= 4; c *= 2) {
    size_t tot = fixedBytes + 2 * ((size_t)(MROWS / c) * 1024 * 2);
    if (tot <= ws_size) { nchunk = c; break; }
  }
  const int CH = MROWS / nchunk;

  char* ws = (char*)d_ws;
  size_t off = 0;
  auto alloc = [&](size_t bytes) -> void* {
    void* p = ws + off; off = (off + bytes + 255) & ~(size_t)255; return p;
  };
  ushort_t* entP0 = (ushort_t*)alloc((size_t)MOBJ * 1024 * 2);
  ushort_t* entP1 = (ushort_t*)alloc((size_t)MOBJ * 1024 * 2);
  float* UV = (float*)alloc((size_t)MOBJ * 1024 * 4);
  ushort_t* eff = (ushort_t*)alloc((size_t)MROWS * 256 * 2);
  ushort_t* agg = (ushort_t*)alloc((size_t)MOBJ * 256 * 2);
  ushort_t* G   = (ushort_t*)alloc((size_t)MOBJ * 1024 * 2);
  ushort_t* WUVt = (ushort_t*)alloc((size_t)1024 * 1536 * 2);
  ushort_t* Wr2t = (ushort_t*)alloc((size_t)512 * 1536 * 2);
  ushort_t* Wr3t = (ushort_t*)alloc((size_t)128 * 1536 * 2);
  ushort_t* Wr4t = (ushort_t*)alloc((size_t)128 * 384 * 2);
  ushort_t* Wo1t = (ushort_t*)alloc((size_t)512 * 1920 * 2);
  ushort_t* Wo2t = (ushort_t*)alloc((size_t)512 * 1536 * 2);
  int* srcN = (int*)alloc((size_t)MROWS * 4);
  int* dstN = (int*)alloc((size_t)MROWS * 4);
  ushort_t* H1c = (ushort_t*)alloc((size_t)CH * 1024 * 2);
  ushort_t* H2c = (ushort_t*)alloc((size_t)CH * 1024 * 2);
  (void)in_sizes; (void)n_in; (void)out_size;

  tr_uv_k<<<(1024 * 512 + 255) / 256, 256, 0, stream>>>(Wr1, WUVt);
  transpose_cvt_split_k<<<(512 * 512 + 255) / 256, 256, 0, stream>>>(Wr2, Wr2t, 512, 512);
  transpose_cvt_split_k<<<(512 * 128 + 255) / 256, 256, 0, stream>>>(Wr3, Wr3t, 512, 128);
  transpose_cvt_split_k<<<(128 * 128 + 255) / 256, 256, 0, stream>>>(Wr4, Wr4t, 128, 128);
  transpose_cvt_split_k<<<(640 * 512 + 255) / 256, 256, 0, stream>>>(Wo1, Wo1t, 640, 512);
  transpose_cvt_split_k<<<(512 * 512 + 255) / 256, 256, 0, stream>>>(Wo2, Wo2t, 512, 512);
  tables_k<<<(MROWS + 255) / 256, 256, 0, stream>>>(srcN, dstN);
  cvt_split_k<<<(MOBJ * D_ + 255) / 256, 256, 0, stream>>>(entity, entP0, MOBJ * D_, D_);

  float* outP    = (float*)d_out;
  float* lastEnt = outP + (size_t)B_ * T_ * 8;

  ushort_t* cur = entP0;
  ushort_t* nxt = entP1;
  for (int t = 0; t < T_; ++t) {
    // UV = ent @ [Wr1_top | Wr1_bot]  (f32 out)  TM=32,TN=128 -> 512 blocks
    gemm_k<0, false, false, true, 32, 128><<<dim3(8, MOBJ / 32), 256, 0, stream>>>(
        cur, nullptr, WUVt, nullptr, nullptr, UV, MOBJ, 1024, 512);

    for (int c = 0; c < nchunk; ++c) {
      const long r0 = (long)c * CH;
      assemble_h1_k<<<CH / 2, 256, 0, stream>>>(UV, srcN, dstN, br1, H1c, r0);
      gemm2_8ph_k<<<dim3(2, CH / 256), 512, 0, stream>>>(H1c, Wr2t, br2, H2c, CH);
      gemm34_k<<<dim3(1, CH / 128), 256, 0, stream>>>(
          H2c, Wr3t, br3, Wr4t, br4, eff + r0 * 256);
    }
    scatter_k<<<MOBJ, 128, 0, stream>>>(eff, agg);
    // GEMM5: TM=32,TN=64 -> 512 blocks
    gemm_k<2, true, true, false, 32, 64><<<dim3(8, MOBJ / 32), 256, 0, stream>>>(
        cur, agg, Wo1t, bo1, G, nullptr, MOBJ, 512, 640);
    // GEMM6: TM=32,TN=64 -> 512 blocks
    float* cf = (t == T_ - 1) ? lastEnt : nullptr;
    gemm_k<0, false, true, true, 32, 64><<<dim3(8, MOBJ / 32), 256, 0, stream>>>(
        G, nullptr, Wo2t, bo2, nxt, cf, MOBJ, 512, 512);
    head_k<<<256, 64, 0, stream>>>(nxt, Wl, bl, outP, t);

    ushort_t* tmp = cur; cur = nxt; nxt = tmp;
  }
}

// Round 11
// 4324.031 us; speedup vs baseline: 1.3820x; 1.1494x over previous
//
#include <hip/hip_runtime.h>
#include <stdint.h>
#include <stddef.h>

// ---------- constants ----------
#define B_    64
#define N_    32
#define NREL_ 992
#define D_    512
#define E_    128
#define H_    512
#define T_    16
#define MROWS (B_ * NREL_)   // 63488
#define MOBJ  (B_ * N_)      // 2048

typedef unsigned short ushort_t;
typedef __attribute__((ext_vector_type(8))) short bf16x8;   // 8 bf16 = 4 VGPRs (MFMA A/B frag)
typedef __attribute__((ext_vector_type(4))) float f32x4;    // MFMA C/D frag

typedef __attribute__((address_space(1))) const void gvoid;
typedef __attribute__((address_space(3))) void lvoid;

__device__ __forceinline__ float bf2f(ushort_t u) {
  union { unsigned int i; float f; } v; v.i = ((unsigned int)u) << 16; return v.f;
}
__device__ __forceinline__ ushort_t f2bf(float f) {   // round-to-nearest-even
  union { float f; unsigned int i; } v; v.f = f;
  unsigned int u = v.i;
  u += 0x7FFFu + ((u >> 16) & 1u);
  return (ushort_t)(u >> 16);
}
__device__ __forceinline__ void gload_lds16(const void* g, void* l) {
  __builtin_amdgcn_global_load_lds((gvoid*)g, (lvoid*)l, 16, 0, 0);
}

// ---------- TMxTN MFMA GEMM, 3xBF16 fp32 emulation (R10, verified) ----------
template<int MODE, bool RELU, bool WBF16, bool WF32, int TM, int TN>
__global__ __launch_bounds__(256) void gemm_k(
    const ushort_t* __restrict__ A, const ushort_t* __restrict__ A2,
    const ushort_t* __restrict__ Bt, const float* __restrict__ bias,
    ushort_t* __restrict__ C, float* __restrict__ Cf,
    int M, int N, int K)
{
  constexpr int MI = (TM + 31) / 32;
  constexpr int NB = TN / 32;
  constexpr int NJ = TN / 32;
  constexpr int AF = (TM >= 64) ? TM / 32 : 1;
  __shared__ ushort_t As[2][TM * 64];
  __shared__ ushort_t Bs[2][TN * 64];

  const int tid  = threadIdx.x;
  const int lane = tid & 63;
  const int wave = tid >> 6;

  const int nwg  = gridDim.x * gridDim.y;
  const int orig = blockIdx.y * gridDim.x + blockIdx.x;
  const int xcd  = orig & 7;
  const int q    = nwg >> 3, r = nwg & 7;
  const int nid  = (xcd < r ? xcd * (q + 1) : r * (q + 1) + (xcd - r) * q) + (orig >> 3);
  const int m0 = (nid / gridDim.x) * TM;
  const int n0 = (nid % gridDim.x) * TN;

  const int wr = (wave >> 1) * (TM / 2);
  const int wc = (wave & 1) * (TN / 2);

  const int srow = tid >> 3;
  const int scol = (((tid & 7) ^ (srow & 7)) * 8);

  long aoff[MI]; long aoff2[MI];
#pragma unroll
  for (int rr = 0; rr < MI; ++rr) {
    int m = m0 + rr * 32 + srow;
    if (MODE == 0) { aoff[rr] = (long)m * (2 * K) + scol; aoff2[rr] = 0; }
    else           { aoff[rr] = (long)m * 1024 + scol; aoff2[rr] = (long)m * 256 + scol; }
  }
  long boff[NB];
#pragma unroll
  for (int rr = 0; rr < NB; ++rr) boff[rr] = (long)(n0 + rr * 32 + srow) * (3 * K) + scol;

  const int NT = (3 * K) >> 6;

  auto stage = [&](int kt, int b) {
    const int kpp = kt * 64;
    const int seg = (kpp >= 2 * K) ? 2 : ((kpp >= K) ? 1 : 0);
    const int k   = kpp - seg * K;
    const bool lop = (seg == 1);
#pragma unroll
    for (int rr = 0; rr < MI; ++rr) {
      const ushort_t* src;
      if (MODE == 0) {
        src = A + aoff[rr] + (lop ? K : 0) + k;
      } else {
        if (k < 512) src = A  + aoff[rr]  + (lop ? 512 : 0) + k;
        else         src = A2 + aoff2[rr] + (lop ? 128 : 0) + (k - 512);
      }
      gload_lds16(src, &As[b][(rr * 32 + wave * 8) * 64]);
    }
#pragma unroll
    for (int rr = 0; rr < NB; ++rr)
      gload_lds16(Bt + boff[rr] + kpp, &Bs[b][(rr * 32 + wave * 8) * 64]);
  };

  f32x4 zero = {0.f, 0.f, 0.f, 0.f};
  f32x4 acc[AF][NJ];
#pragma unroll
  for (int i = 0; i < AF; ++i)
#pragma unroll
    for (int j = 0; j < NJ; ++j) acc[i][j] = zero;

  stage(0, 0);
  if (NT > 1) stage(1, 1);

  for (int kt = 0; kt < NT; ++kt) {
    const int b = kt & 1;
    if (kt + 1 < NT) {
      if constexpr (MI + NB == 8)      asm volatile("s_waitcnt vmcnt(8)" ::: "memory");
      else if constexpr (MI + NB == 6) asm volatile("s_waitcnt vmcnt(6)" ::: "memory");
      else if constexpr (MI + NB == 5) asm volatile("s_waitcnt vmcnt(5)" ::: "memory");
      else if constexpr (MI + NB == 4) asm volatile("s_waitcnt vmcnt(4)" ::: "memory");
      else                             asm volatile("s_waitcnt vmcnt(3)" ::: "memory");
    } else {
      asm volatile("s_waitcnt vmcnt(0)" ::: "memory");
    }
    __builtin_amdgcn_s_barrier();
    asm volatile("" ::: "memory");

#pragma unroll
    for (int kk = 0; kk < 2; ++kk) {
      const int cel = (((kk * 4 + (lane >> 4)) ^ (lane & 7)) << 3);
      bf16x8 af[AF];
#pragma unroll
      for (int i = 0; i < AF; ++i)
        af[i] = *(const bf16x8*)&As[b][(wr + i * 16 + (lane & 15)) * 64 + cel];
#pragma unroll
      for (int jh = 0; jh < (NJ + 1) / 2; ++jh) {
        bf16x8 bfr[2];
#pragma unroll
        for (int jj = 0; jj < 2 && jh * 2 + jj < NJ; ++jj)
          bfr[jj] = *(const bf16x8*)&Bs[b][(wc + (jh * 2 + jj) * 16 + (lane & 15)) * 64 + cel];
        __builtin_amdgcn_s_setprio(1);
#pragma unroll
        for (int i = 0; i < AF; ++i)
#pragma unroll
          for (int jj = 0; jj < 2 && jh * 2 + jj < NJ; ++jj)
            acc[i][jh * 2 + jj] =
                __builtin_amdgcn_mfma_f32_16x16x32_bf16(af[i], bfr[jj], acc[i][jh * 2 + jj], 0, 0, 0);
        __builtin_amdgcn_s_setprio(0);
      }
    }

    asm volatile("" ::: "memory");
    __builtin_amdgcn_s_barrier();
    asm volatile("" ::: "memory");
    if (kt + 2 < NT) stage(kt + 2, b);
  }

  const long strideC = 2 * (long)N;
#pragma unroll
  for (int j = 0; j < NJ; ++j) {
    const int col = n0 + wc + j * 16 + (lane & 15);
    const float bv = bias ? bias[col] : 0.f;
#pragma unroll
    for (int i = 0; i < AF; ++i) {
      const int rowb = m0 + wr + i * 16 + (lane >> 4) * 4;
#pragma unroll
      for (int rr = 0; rr < 4; ++rr) {
        float v = acc[i][j][rr] + bv;
        if (RELU) v = fmaxf(v, 0.f);
        if (WBF16) {
          const ushort_t hi = f2bf(v);
          const float lof = v - bf2f(hi);
          C[(long)(rowb + rr) * strideC + col]     = hi;
          C[(long)(rowb + rr) * strideC + N + col] = f2bf(lof);
        }
        if (WF32) { if (Cf) Cf[(long)(rowb + rr) * N + col] = v; }
      }
    }
  }
}

// ---------- FUSED assemble+GEMM2: H2 = relu(H1 @ Wr2 + b2) ----------
// H1[m][k] = relu(UV[src[m]][k] + UV[dst[m]][512+k] + b1[k]) computed ON THE
// FLY into LDS (no H1 materialization in HBM). 3-term emulation is
// kb-INTERLEAVED: per 32-col K-block, v computed ONCE -> Ahi+Alo both staged;
// products per set: hi*Bhi, hi*Blo, lo*Bhi (96 MFMA/wave/set, VALU ~320cyc
// hides under MFMA ~460cyc). 256x256 tile, 8 waves, BK=32, double-buffered
// (8 x 16KB = 128KB LDS). Stage issues UV f32 loads FIRST then B gload_lds so
// in-stage vmcnt(4) covers the gathers; phase-top vmcnt(4)+lgkmcnt(0).
// Accumulation is a reorder of the same 48 partials (threshold has 4.3x room).
__global__ __launch_bounds__(512) void gemm12_k(
    const float* __restrict__ UV,     // [2048][1024] f32 = [U|V]
    const int* __restrict__ srcN, const int* __restrict__ dstN,
    const float* __restrict__ b1,
    const ushort_t* __restrict__ Bt,  // Wr2t [512][1536] = [hi|hi|lo]
    const float* __restrict__ b2,
    ushort_t* __restrict__ C,         // H2 split [M][1024]
    int M)
{
  __shared__ ushort_t Ah[2][256 * 32];
  __shared__ ushort_t Al[2][256 * 32];
  __shared__ ushort_t Bh[2][256 * 32];
  __shared__ ushort_t Bl[2][256 * 32];

  const int tid  = threadIdx.x;
  const int lane = tid & 63;
  const int wave = tid >> 6;
  const int l15  = lane & 15;

  const int nwg  = gridDim.x * gridDim.y;
  const int orig = blockIdx.y * gridDim.x + blockIdx.x;
  const int xcd  = orig & 7;
  const int q    = nwg >> 3, r = nwg & 7;
  const int nid  = (xcd < r ? xcd * (q + 1) : r * (q + 1) + (xcd - r) * q) + (orig >> 3);
  const int m0 = (nid / gridDim.x) * 256;
  const int n0 = (nid % gridDim.x) * 256;

  const int wr = (wave >> 2) * 128;   // 0 or 128
  const int wc = (wave & 3) * 64;     // 0,64,128,192

  // B staging: trow 0..127, 2 row-rounds, pre-swizzled source col (32-col rows)
  const int trow = tid >> 2;
  const int scol = (((tid & 3) ^ ((trow >> 1) & 3)) * 8);
  long boffh[2], boffl[2];
#pragma unroll
  for (int rr = 0; rr < 2; ++rr) {
    boffh[rr] = (long)(n0 + rr * 128 + trow) * 1536 + scol;
    boffl[rr] = boffh[rr] + 1024;
  }

  // A compute-staging: thread owns row arow (fixed), 16 cols at ac0
  const int arow = tid >> 1;
  const int ac0  = (tid & 1) * 16;
  const long srcBase = (long)srcN[m0 + arow] * 1024;
  const long dstBase = (long)dstN[m0 + arow] * 1024 + 512;
  const int wsl0 = ((ac0 >> 3) + 0) ^ ((arow >> 1) & 3);   // phys 16B slots
  const int wsl1 = ((ac0 >> 3) + 1) ^ ((arow >> 1) & 3);

  auto stage = [&](int kb, int b) {
    const int k0 = kb * 32 + ac0;
    // UV gathers + bias FIRST (12 loads) ...
    const float4 u0 = *(const float4*)&UV[srcBase + k0 + 0];
    const float4 u1 = *(const float4*)&UV[srcBase + k0 + 4];
    const float4 u2 = *(const float4*)&UV[srcBase + k0 + 8];
    const float4 u3 = *(const float4*)&UV[srcBase + k0 + 12];
    const float4 w0 = *(const float4*)&UV[dstBase + k0 + 0];
    const float4 w1 = *(const float4*)&UV[dstBase + k0 + 4];
    const float4 w2 = *(const float4*)&UV[dstBase + k0 + 8];
    const float4 w3 = *(const float4*)&UV[dstBase + k0 + 12];
    const float4 c0 = *(const float4*)&b1[k0 + 0];
    const float4 c1 = *(const float4*)&b1[k0 + 4];
    const float4 c2 = *(const float4*)&b1[k0 + 8];
    const float4 c3 = *(const float4*)&b1[k0 + 12];
    // ... then B gload_lds (4) so vmcnt(4) below waits exactly the UV/bias loads
#pragma unroll
    for (int rr = 0; rr < 2; ++rr)
      gload_lds16(Bt + boffh[rr] + kb * 32, &Bh[b][(rr * 128 + wave * 16) * 32]);
#pragma unroll
    for (int rr = 0; rr < 2; ++rr)
      gload_lds16(Bt + boffl[rr] + kb * 32, &Bl[b][(rr * 128 + wave * 16) * 32]);

    ushort_t hibuf[16], lobuf[16];
    const float* uu[4] = {(const float*)&u0, (const float*)&u1, (const float*)&u2, (const float*)&u3};
    const float* ww[4] = {(const float*)&w0, (const float*)&w1, (const float*)&w2, (const float*)&w3};
    const float* cc[4] = {(const float*)&c0, (const float*)&c1, (const float*)&c2, (const float*)&c3};
#pragma unroll
    for (int g = 0; g < 4; ++g)
#pragma unroll
      for (int e = 0; e < 4; ++e) {
        const float v = fmaxf(uu[g][e] + ww[g][e] + cc[g][e], 0.f);
        const ushort_t hi = f2bf(v);
        hibuf[g * 4 + e] = hi;
        lobuf[g * 4 + e] = f2bf(v - bf2f(hi));
      }
    *(bf16x8*)&Ah[b][arow * 32 + wsl0 * 8] = *(bf16x8*)&hibuf[0];
    *(bf16x8*)&Ah[b][arow * 32 + wsl1 * 8] = *(bf16x8*)&hibuf[8];
    *(bf16x8*)&Al[b][arow * 32 + wsl0 * 8] = *(bf16x8*)&lobuf[0];
    *(bf16x8*)&Al[b][arow * 32 + wsl1 * 8] = *(bf16x8*)&lobuf[8];
  };

  f32x4 zero = {0.f, 0.f, 0.f, 0.f};
  f32x4 acc[8][4];
#pragma unroll
  for (int i = 0; i < 8; ++i)
#pragma unroll
    for (int j = 0; j < 4; ++j) acc[i][j] = zero;

  // prologue
  stage(0, 0);
  asm volatile("s_waitcnt vmcnt(4)" ::: "memory");   // stage(0)'s UV done (B in flight)
  stage(1, 1);
  asm volatile("s_waitcnt vmcnt(0) lgkmcnt(0)" ::: "memory");
  __builtin_amdgcn_s_barrier();
  asm volatile("" ::: "memory");

  for (int kb = 0; kb < 16; ++kb) {
    const int b = kb & 1;
    if (kb > 0) {
      if (kb + 1 < 16) asm volatile("s_waitcnt vmcnt(4) lgkmcnt(0)" ::: "memory");
      else             asm volatile("s_waitcnt vmcnt(0) lgkmcnt(0)" ::: "memory");
      __builtin_amdgcn_s_barrier();
      asm volatile("" ::: "memory");
    }

    // cluster 1: hi * Bhi
    bf16x8 ah[8], bh[4];
#pragma unroll
    for (int i = 0; i < 8; ++i) {
      const int row = wr + i * 16 + l15;
      ah[i] = *(const bf16x8*)&Ah[b][row * 32 + (((lane >> 4) ^ ((row >> 1) & 3)) << 3)];
    }
#pragma unroll
    for (int j = 0; j < 4; ++j) {
      const int row = wc + j * 16 + l15;
      bh[j] = *(const bf16x8*)&Bh[b][row * 32 + (((lane >> 4) ^ ((row >> 1) & 3)) << 3)];
    }
    __builtin_amdgcn_s_setprio(1);
#pragma unroll
    for (int i = 0; i < 8; ++i)
#pragma unroll
      for (int j = 0; j < 4; ++j)
        acc[i][j] = __builtin_amdgcn_mfma_f32_16x16x32_bf16(ah[i], bh[j], acc[i][j], 0, 0, 0);
    __builtin_amdgcn_s_setprio(0);

    // cluster 2: hi * Blo (ah reused in registers)
    bf16x8 bl_[4];
#pragma unroll
    for (int j = 0; j < 4; ++j) {
      const int row = wc + j * 16 + l15;
      bl_[j] = *(const bf16x8*)&Bl[b][row * 32 + (((lane >> 4) ^ ((row >> 1) & 3)) << 3)];
    }
    __builtin_amdgcn_s_setprio(1);
#pragma unroll
    for (int i = 0; i < 8; ++i)
#pragma unroll
      for (int j = 0; j < 4; ++j)
        acc[i][j] = __builtin_amdgcn_mfma_f32_16x16x32_bf16(ah[i], bl_[j], acc[i][j], 0, 0, 0);
    __builtin_amdgcn_s_setprio(0);

    // cluster 3: lo * Bhi (bh reused in registers)
    bf16x8 al[8];
#pragma unroll
    for (int i = 0; i < 8; ++i) {
      const int row = wr + i * 16 + l15;
      al[i] = *(const bf16x8*)&Al[b][row * 32 + (((lane >> 4) ^ ((row >> 1) & 3)) << 3)];
    }
    __builtin_amdgcn_s_setprio(1);
#pragma unroll
    for (int i = 0; i < 8; ++i)
#pragma unroll
      for (int j = 0; j < 4; ++j)
        acc[i][j] = __builtin_amdgcn_mfma_f32_16x16x32_bf16(al[i], bh[j], acc[i][j], 0, 0, 0);
    __builtin_amdgcn_s_setprio(0);

    asm volatile("" ::: "memory");
    __builtin_amdgcn_s_barrier();
    asm volatile("" ::: "memory");
    if (kb + 2 < 16) stage(kb + 2, b);
  }

  // epilogue: relu(acc + b2) -> H2 split [row][1024] = [hi512 | lo512]
#pragma unroll
  for (int j = 0; j < 4; ++j) {
    const int col = n0 + wc + j * 16 + l15;
    const float bv = b2[col];
#pragma unroll
    for (int i = 0; i < 8; ++i) {
      const int rowb = m0 + wr + i * 16 + (lane >> 4) * 4;
#pragma unroll
      for (int rr = 0; rr < 4; ++rr) {
        float v = fmaxf(acc[i][j][rr] + bv, 0.f);
        const ushort_t hi = f2bf(v);
        C[(long)(rowb + rr) * 1024 + col]       = hi;
        C[(long)(rowb + rr) * 1024 + 512 + col] = f2bf(v - bf2f(hi));
      }
    }
  }
}

// ---------- fused GEMM3+GEMM4: eff = relu(relu(H2@W3+b3)@W4+b4) ----------
__global__ __launch_bounds__(256) void gemm34_k(
    const ushort_t* __restrict__ A, const ushort_t* __restrict__ W3t,
    const float* __restrict__ b3, const ushort_t* __restrict__ W4t,
    const float* __restrict__ b4, ushort_t* __restrict__ eff)
{
  __shared__ ushort_t SM[4][128 * 64];
  ushort_t* SMf = &SM[0][0];

  const int tid  = threadIdx.x;
  const int lane = tid & 63;
  const int wave = tid >> 6;

  const int nwg  = gridDim.y;
  const int orig = blockIdx.y;
  const int xcd  = orig & 7;
  const int q    = nwg >> 3, r = nwg & 7;
  const int nid  = (xcd < r ? xcd * (q + 1) : r * (q + 1) + (xcd - r) * q) + (orig >> 3);
  const int m0   = nid * 128;

  const int wr = (wave >> 1) * 64;
  const int wc = (wave & 1) * 64;
  const int srow = tid >> 3;
  const int scol = (((tid & 7) ^ (srow & 7)) * 8);

  long aoff[4];
#pragma unroll
  for (int rr = 0; rr < 4; ++rr) aoff[rr] = (long)(m0 + rr * 32 + srow) * 1024 + scol;
  long boff[4];
#pragma unroll
  for (int rr = 0; rr < 4; ++rr) boff[rr] = (long)(rr * 32 + srow) * 1536 + scol;

  auto stage = [&](int kt, int b) {
    const int kpp = kt * 64;
    const int seg = (kpp >= 1024) ? 2 : ((kpp >= 512) ? 1 : 0);
    const int k   = kpp - seg * 512;
    const bool lop = (seg == 1);
#pragma unroll
    for (int rr = 0; rr < 4; ++rr)
      gload_lds16(A + aoff[rr] + (lop ? 512 : 0) + k, &SM[b][(rr * 32 + wave * 8) * 64]);
#pragma unroll
    for (int rr = 0; rr < 4; ++rr)
      gload_lds16(W3t + boff[rr] + kpp, &SM[2 + b][(rr * 32 + wave * 8) * 64]);
  };

  f32x4 zero = {0.f, 0.f, 0.f, 0.f};
  f32x4 acc[4][4];
#pragma unroll
  for (int i = 0; i < 4; ++i)
#pragma unroll
    for (int j = 0; j < 4; ++j) acc[i][j] = zero;

  stage(0, 0);
  stage(1, 1);

  for (int kt = 0; kt < 24; ++kt) {
    const int b = kt & 1;
    if (kt + 1 < 24) asm volatile("s_waitcnt vmcnt(8)" ::: "memory");
    else             asm volatile("s_waitcnt vmcnt(0)" ::: "memory");
    __builtin_amdgcn_s_barrier();
    asm volatile("" ::: "memory");

#pragma unroll
    for (int kk = 0; kk < 2; ++kk) {
      const int cel = (((kk * 4 + (lane >> 4)) ^ (lane & 7)) << 3);
      bf16x8 af[4];
#pragma unroll
      for (int i = 0; i < 4; ++i)
        af[i] = *(const bf16x8*)&SM[b][(wr + i * 16 + (lane & 15)) * 64 + cel];
#pragma unroll
      for (int jh = 0; jh < 2; ++jh) {
        bf16x8 bfr[2];
#pragma unroll
        for (int jj = 0; jj < 2; ++jj)
          bfr[jj] = *(const bf16x8*)&SM[2 + b][(wc + (jh * 2 + jj) * 16 + (lane & 15)) * 64 + cel];
        __builtin_amdgcn_s_setprio(1);
#pragma unroll
        for (int i = 0; i < 4; ++i)
#pragma unroll
          for (int jj = 0; jj < 2; ++jj)
            acc[i][jh * 2 + jj] =
                __builtin_amdgcn_mfma_f32_16x16x32_bf16(af[i], bfr[jj], acc[i][jh * 2 + jj], 0, 0, 0);
        __builtin_amdgcn_s_setprio(0);
      }
    }

    asm volatile("" ::: "memory");
    __builtin_amdgcn_s_barrier();
    asm volatile("" ::: "memory");
    if (kt + 2 < 24) stage(kt + 2, b);
  }

#pragma unroll
  for (int j = 0; j < 4; ++j) {
    const int col = wc + j * 16 + (lane & 15);
    const float bv = b3[col];
    const int thi = col >> 6, c = col & 63;
#pragma unroll
    for (int i = 0; i < 4; ++i) {
      const int rowb = wr + i * 16 + (lane >> 4) * 4;
#pragma unroll
      for (int rr = 0; rr < 4; ++rr) {
        const int row = rowb + rr;
        float v = fmaxf(acc[i][j][rr] + bv, 0.f);
        const ushort_t hi = f2bf(v);
        const ushort_t lo = f2bf(v - bf2f(hi));
        const int slot = ((c >> 3) ^ (row & 7)) * 8 + (c & 7);
        SMf[(thi * 128 + row) * 64 + slot]       = hi;
        SMf[((2 + thi) * 128 + row) * 64 + slot] = lo;
      }
    }
  }
  asm volatile("s_waitcnt lgkmcnt(0)" ::: "memory");
  __builtin_amdgcn_sched_barrier(0);
  __builtin_amdgcn_s_barrier();
  asm volatile("" ::: "memory");

  f32x4 acc2[4][4];
#pragma unroll
  for (int i = 0; i < 4; ++i)
#pragma unroll
    for (int j = 0; j < 4; ++j) acc2[i][j] = zero;

#pragma unroll
  for (int kt2 = 0; kt2 < 6; ++kt2) {
    const int phys = kt2 & 3;
#pragma unroll
    for (int kk = 0; kk < 2; ++kk) {
      const int cel = (((kk * 4 + (lane >> 4)) ^ (lane & 7)) << 3);
      bf16x8 af[4];
#pragma unroll
      for (int i = 0; i < 4; ++i)
        af[i] = *(const bf16x8*)&SMf[(phys * 128 + wr + i * 16 + (lane & 15)) * 64 + cel];
#pragma unroll
      for (int jh = 0; jh < 2; ++jh) {
        bf16x8 bfr[2];
#pragma unroll
        for (int jj = 0; jj < 2; ++jj) {
          const int col2 = wc + (jh * 2 + jj) * 16 + (lane & 15);
          bfr[jj] = *(const bf16x8*)&W4t[(long)col2 * 384 + kt2 * 64 + kk * 32 + (lane >> 4) * 8];
        }
        __builtin_amdgcn_s_setprio(1);
#pragma unroll
        for (int i = 0; i < 4; ++i)
#pragma unroll
          for (int jj = 0; jj < 2; ++jj)
            acc2[i][jh * 2 + jj] =
                __builtin_amdgcn_mfma_f32_16x16x32_bf16(af[i], bfr[jj], acc2[i][jh * 2 + jj], 0, 0, 0);
        __builtin_amdgcn_s_setprio(0);
      }
    }
  }

#pragma unroll
  for (int j = 0; j < 4; ++j) {
    const int col = wc + j * 16 + (lane & 15);
    const float bv = b4[col];
#pragma unroll
    for (int i = 0; i < 4; ++i) {
      const int rowb = m0 + wr + i * 16 + (lane >> 4) * 4;
#pragma unroll
      for (int rr = 0; rr < 4; ++rr) {
        float v = fmaxf(acc2[i][j][rr] + bv, 0.f);
        const ushort_t hi = f2bf(v);
        eff[(long)(rowb + rr) * 256 + col]       = hi;
        eff[(long)(rowb + rr) * 256 + 128 + col] = f2bf(v - bf2f(hi));
      }
    }
  }
}

// ---------- helpers ----------
__global__ void cvt_split_k(const float* __restrict__ x, ushort_t* __restrict__ y,
                            int total, int W) {
  int i = blockIdx.x * 256 + threadIdx.x;
  if (i >= total) return;
  int row = i / W, k = i - row * W;
  float v = x[i];
  ushort_t hi = f2bf(v);
  float lof = v - bf2f(hi);
  y[(long)row * (2 * W) + k]     = hi;
  y[(long)row * (2 * W) + W + k] = f2bf(lof);
}

__global__ void transpose_cvt_split_k(const float* __restrict__ W, ushort_t* __restrict__ Bt,
                                      int K, int N) {
  int idx = blockIdx.x * 256 + threadIdx.x;
  if (idx >= K * N) return;
  int k = idx / N, n = idx - k * N;
  float v = W[idx];
  ushort_t hi = f2bf(v);
  float lof = v - bf2f(hi);
  ushort_t lo = f2bf(lof);
  long base = (long)n * (3 * K);
  Bt[base + k]         = hi;
  Bt[base + K + k]     = hi;
  Bt[base + 2 * K + k] = lo;
}

__global__ void tr_uv_k(const float* __restrict__ W, ushort_t* __restrict__ Bt) {
  int idx = blockIdx.x * 256 + threadIdx.x;
  if (idx >= 1024 * 512) return;
  int n = idx >> 9, k = idx & 511;
  float v = (n < 512) ? W[(long)k * 512 + n] : W[(long)(512 + k) * 512 + (n - 512)];
  ushort_t hi = f2bf(v);
  float lof = v - bf2f(hi);
  long base = (long)n * 1536;
  Bt[base + k]        = hi;
  Bt[base + 512 + k]  = hi;
  Bt[base + 1024 + k] = f2bf(lof);
}

__global__ void tables_k(int* __restrict__ srcN, int* __restrict__ dstN) {
  int m = blockIdx.x * 256 + threadIdx.x;
  if (m >= MROWS) return;
  int b = m / NREL_;
  int e = m - b * NREL_;
  int i = e / 31;
  int jj = e - i * 31;
  int j = jj + (jj >= i ? 1 : 0);
  srcN[m] = b * N_ + i;
  dstN[m] = b * N_ + j;
}

__global__ void scatter_k(const ushort_t* __restrict__ eff, ushort_t* __restrict__ agg) {
  int bn = blockIdx.x;
  int b = bn >> 5, n = bn & 31, f = threadIdx.x;
  float s = 0.f;
#pragma unroll
  for (int i = 0; i < N_; ++i) {
    if (i == n) continue;
    int jj = (n < i) ? n : (n - 1);
    int e = i * 31 + jj;
    long base = ((long)b * NREL_ + e) * 256;
    s += bf2f(eff[base + f]) + bf2f(eff[base + 128 + f]);
  }
  long obase = ((long)b * N_ + n) * 256;
  ushort_t hi = f2bf(s);
  agg[obase + f]       = hi;
  agg[obase + 128 + f] = f2bf(s - bf2f(hi));
}

__global__ void head_k(const ushort_t* __restrict__ ent, const float* __restrict__ Wl,
                       const float* __restrict__ bl, float* __restrict__ out, int t) {
  int b = blockIdx.x >> 2, n = blockIdx.x & 3, lane = threadIdx.x;
  const ushort_t* e = ent + (long)(b * N_ + n) * 1024;
  float a0 = 0.f, a1 = 0.f;
  for (int k = lane; k < D_; k += 64) {
    float v = bf2f(e[k]) + bf2f(e[512 + k]);
    a0 += v * Wl[2 * k]; a1 += v * Wl[2 * k + 1];
  }
#pragma unroll
  for (int s = 32; s > 0; s >>= 1) { a0 += __shfl_down(a0, s); a1 += __shfl_down(a1, s); }
  if (lane == 0) {
    out[((long)b * T_ + t) * 8 + n * 2 + 0] = a0 + bl[0];
    out[((long)b * T_ + t) * 8 + n * 2 + 1] = a1 + bl[1];
  }
}

// ---------- launch ----------
extern "C" void kernel_launch(void* const* d_in, const int* in_sizes, int n_in,
                              void* d_out, int out_size, void* d_ws, size_t ws_size,
                              hipStream_t stream) {
  const float* entity = (const float*)d_in[0];
  const float* Wr1 = (const float*)d_in[3];  const float* br1 = (const float*)d_in[4];
  const float* Wr2 = (const float*)d_in[5];  const float* br2 = (const float*)d_in[6];
  const float* Wr3 = (const float*)d_in[7];  const float* br3 = (const float*)d_in[8];
  const float* Wr4 = (const float*)d_in[9];  const float* br4 = (const float*)d_in[10];
  const float* Wo1 = (const float*)d_in[11]; const float* bo1 = (const float*)d_in[12];
  const float* Wo2 = (const float*)d_in[13]; const float* bo2 = (const float*)d_in[14];
  const float* Wl  = (const float*)d_in[15]; const float* bl  = (const float*)d_in[16];

  // fixed allocs ~72MB; chunk buffer = H2c only
  const size_t fixedBytes = (size_t)72 * 1024 * 1024;
  int nchunk = 4;
  for (int c = 1; c <= 4; c *= 2) {
    size_t tot = fixedBytes + ((size_t)(MROWS / c) * 1024 * 2);
    if (tot <= ws_size) { nchunk = c; break; }
  }
  const int CH = MROWS / nchunk;

  char* ws = (char*)d_ws;
  size_t off = 0;
  auto alloc = [&](size_t bytes) -> void* {
    void* p = ws + off; off = (off + bytes + 255) & ~(size_t)255; return p;
  };
  ushort_t* entP0 = (ushort_t*)alloc((size_t)MOBJ * 1024 * 2);
  ushort_t* entP1 = (ushort_t*)alloc((size_t)MOBJ * 1024 * 2);
  float* UV = (float*)alloc((size_t)MOBJ * 1024 * 4);
  ushort_t* eff = (ushort_t*)alloc((size_t)MROWS * 256 * 2);
  ushort_t* agg = (ushort_t*)alloc((size_t)MOBJ * 256 * 2);
  ushort_t* G   = (ushort_t*)alloc((size_t)MOBJ * 1024 * 2);
  ushort_t* WUVt = (ushort_t*)alloc((size_t)1024 * 1536 * 2);
  ushort_t* Wr2t = (ushort_t*)alloc((size_t)512 * 1536 * 2);
  ushort_t* Wr3t = (ushort_t*)alloc((size_t)128 * 1536 * 2);
  ushort_t* Wr4t = (ushort_t*)alloc((size_t)128 * 384 * 2);
  ushort_t* Wo1t = (ushort_t*)alloc((size_t)512 * 1920 * 2);
  ushort_t* Wo2t = (ushort_t*)alloc((size_t)512 * 1536 * 2);
  int* srcN = (int*)alloc((size_t)MROWS * 4);
  int* dstN = (int*)alloc((size_t)MROWS * 4);
  ushort_t* H2c = (ushort_t*)alloc((size_t)CH * 1024 * 2);
  (void)in_sizes; (void)n_in; (void)out_size;

  tr_uv_k<<<(1024 * 512 + 255) / 256, 256, 0, stream>>>(Wr1, WUVt);
  transpose_cvt_split_k<<<(512 * 512 + 255) / 256, 256, 0, stream>>>(Wr2, Wr2t, 512, 512);
  transpose_cvt_split_k<<<(512 * 128 + 255) / 256, 256, 0, stream>>>(Wr3, Wr3t, 512, 128);
  transpose_cvt_split_k<<<(128 * 128 + 255) / 256, 256, 0, stream>>>(Wr4, Wr4t, 128, 128);
  transpose_cvt_split_k<<<(640 * 512 + 255) / 256, 256, 0, stream>>>(Wo1, Wo1t, 640, 512);
  transpose_cvt_split_k<<<(512 * 512 + 255) / 256, 256, 0, stream>>>(Wo2, Wo2t, 512, 512);
  tables_k<<<(MROWS + 255) / 256, 256, 0, stream>>>(srcN, dstN);
  cvt_split_k<<<(MOBJ * D_ + 255) / 256, 256, 0, stream>>>(entity, entP0, MOBJ * D_, D_);

  float* outP    = (float*)d_out;
  float* lastEnt = outP + (size_t)B_ * T_ * 8;

  ushort_t* cur = entP0;
  ushort_t* nxt = entP1;
  for (int t = 0; t < T_; ++t) {
    // UV = ent @ [Wr1_top | Wr1_bot]  (f32 out)  TM=32,TN=128 -> 512 blocks
    gemm_k<0, false, false, true, 32, 128><<<dim3(8, MOBJ / 32), 256, 0, stream>>>(
        cur, nullptr, WUVt, nullptr, nullptr, UV, MOBJ, 1024, 512);

    for (int c = 0; c < nchunk; ++c) {
      const long r0 = (long)c * CH;
      // FUSED assemble + GEMM2 -> H2c
      gemm12_k<<<dim3(2, CH / 256), 512, 0, stream>>>(
          UV, srcN + r0, dstN + r0, br1, Wr2t, br2, H2c, CH);
      gemm34_k<<<dim3(1, CH / 128), 256, 0, stream>>>(
          H2c, Wr3t, br3, Wr4t, br4, eff + r0 * 256);
    }
    scatter_k<<<MOBJ, 128, 0, stream>>>(eff, agg);
    gemm_k<2, true, true, false, 32, 64><<<dim3(8, MOBJ / 32), 256, 0, stream>>>(
        cur, agg, Wo1t, bo1, G, nullptr, MOBJ, 512, 640);
    float* cf = (t == T_ - 1) ? lastEnt : nullptr;
    gemm_k<0, false, true, true, 32, 64><<<dim3(8, MOBJ / 32), 256, 0, stream>>>(
        G, nullptr, Wo2t, bo2, nxt, cf, MOBJ, 512, 512);
    head_k<<<256, 64, 0, stream>>>(nxt, Wl, bl, outP, t);

    ushort_t* tmp = cur; cur = nxt; nxt = tmp;
  }
}